// Round 15
// baseline (1286.898 us; speedup 1.0000x reference)
//
#include <hip/hip_runtime.h>
#include <hip/hip_bf16.h>

// ---------- types ----------
typedef __attribute__((ext_vector_type(8))) short short8;   // 8 x bf16 bits
typedef __attribute__((ext_vector_type(4))) float f32x4;

__device__ __forceinline__ ushort f2bf(float f) {
  uint32_t u = __float_as_uint(f);
  uint32_t r = (u + 0x7FFFu + ((u >> 16) & 1u)) >> 16;
  return (ushort)r;
}
__device__ __forceinline__ float bf2f(ushort u) {
  return __uint_as_float(((uint32_t)u) << 16);
}

__device__ __forceinline__ void gload_lds16(const ushort* g, ushort* l) {
  __builtin_amdgcn_global_load_lds(
      (const __attribute__((address_space(1))) void*)g,
      (__attribute__((address_space(3))) void*)l, 16, 0, 0);
}

__device__ __forceinline__ f32x4 mfma16(short8 a, short8 b, f32x4 c) {
  return __builtin_amdgcn_mfma_f32_16x16x32_bf16(a, b, c, 0, 0, 0);
}

#define BAR() __builtin_amdgcn_s_barrier()
#define WAIT_LGKM()                                        \
  do {                                                     \
    asm volatile("s_waitcnt lgkmcnt(0)" ::: "memory");     \
    __builtin_amdgcn_sched_barrier(0);                     \
  } while (0)
#define WAIT_VM0()                                         \
  do {                                                     \
    asm volatile("s_waitcnt vmcnt(0)" ::: "memory");       \
    __builtin_amdgcn_sched_barrier(0);                     \
  } while (0)
#define WAIT_VM4()                                         \
  do {                                                     \
    asm volatile("s_waitcnt vmcnt(4)" ::: "memory");       \
    __builtin_amdgcn_sched_barrier(0);                     \
  } while (0)

// ---------- transpose + fp32->bf16 convert: W[K][N] -> WT[p(N)][K] ----------
// 64x64 tiles, float4 loads / ushort4 stores. blockIdx.z = layer.
// mode 0: p(n)=n.  mode 1 (gate/up interleave): p(n)= n<4096 ? 2n : 2(n-4096)+1
__global__ __launch_bounds__(256)
void transpose_conv_kernel(const float* __restrict__ W, ushort* __restrict__ WT,
                           const int K, const int N, const int mode) {
  const size_t lofs = (size_t)blockIdx.z * K * N;
  W += lofs;
  WT += lofs;
  __shared__ float tile[64][65];
  const int n0 = blockIdx.x * 64;
  const int k0 = blockIdx.y * 64;
  const int t = threadIdx.x;
#pragma unroll
  for (int j = 0; j < 4; ++j) {
    const int idx = j * 1024 + t * 4;
    const int kk = idx >> 6, nn = idx & 63;
    *(float4*)&tile[kk][nn] = *(const float4*)&W[(size_t)(k0 + kk) * N + n0 + nn];
  }
  __syncthreads();
#pragma unroll
  for (int j = 0; j < 4; ++j) {
    const int idx = j * 1024 + t * 4;
    const int nn = idx >> 6, kk = idx & 63;
    int rr = n0 + nn;
    if (mode == 1) rr = (rr < 4096) ? (2 * rr) : (2 * (rr - 4096) + 1);
    ushort4 o;
    o.x = f2bf(tile[kk + 0][nn]);
    o.y = f2bf(tile[kk + 1][nn]);
    o.z = f2bf(tile[kk + 2][nn]);
    o.w = f2bf(tile[kk + 3][nn]);
    *(ushort4*)&WT[(size_t)rr * K + k0 + kk] = o;
  }
}

// ---------- RoPE cos/sin table ----------
__global__ __launch_bounds__(256)
void sincos_kernel(float2* __restrict__ cstab) {
  const int idx = blockIdx.x * 256 + threadIdx.x;   // 65536 total
  const int s = idx >> 5, o = idx & 31;
  const float freq = exp2f(-0.41524101186092029f * (float)o);  // 10000^(-o/32)
  const float a = (float)s * freq;
  cstab[idx] = make_float2(cosf(a), sinf(a));
}

// ---------- fused embedding gather + rmsnorm (table row 0 forced to zero) ----------
__global__ __launch_bounds__(256)
void embed_norm_kernel(const int* __restrict__ tokens, const float* __restrict__ table,
                       float* __restrict__ emb, ushort* __restrict__ normed) {
  const int s = blockIdx.x, t = threadIdx.x;
  const int tok = tokens[s];
  float4 v = make_float4(0.f, 0.f, 0.f, 0.f);
  if (tok != 0) v = *(const float4*)&table[(size_t)tok * 1024 + t * 4];
  *(float4*)&emb[(size_t)s * 1024 + t * 4] = v;
  float ss = v.x * v.x + v.y * v.y + v.z * v.z + v.w * v.w;
#pragma unroll
  for (int off = 32; off; off >>= 1) ss += __shfl_xor(ss, off);
  __shared__ float red[4];
  if ((t & 63) == 0) red[t >> 6] = ss;
  __syncthreads();
  const float total = red[0] + red[1] + red[2] + red[3];
  const float sc = rsqrtf(total * (1.f / 1024.f) + 1e-5f);
  ushort4 o;
  o.x = f2bf(v.x * sc); o.y = f2bf(v.y * sc);
  o.z = f2bf(v.z * sc); o.w = f2bf(v.w * sc);
  *(ushort4*)&normed[(size_t)s * 1024 + t * 4] = o;
}

// ---------- rmsnorm over 1024 cols: f32 in -> bf16 out ----------
__global__ __launch_bounds__(256)
void rmsnorm_kernel(const float* __restrict__ x, ushort* __restrict__ out) {
  const int row = blockIdx.x, t = threadIdx.x;
  const float4 v = *(const float4*)&x[(size_t)row * 1024 + t * 4];
  float ss = v.x * v.x + v.y * v.y + v.z * v.z + v.w * v.w;
#pragma unroll
  for (int off = 32; off; off >>= 1) ss += __shfl_xor(ss, off);
  __shared__ float red[4];
  if ((t & 63) == 0) red[t >> 6] = ss;
  __syncthreads();
  const float total = red[0] + red[1] + red[2] + red[3];
  const float sc = rsqrtf(total * (1.f / 1024.f) + 1e-5f);
  ushort4 o;
  o.x = f2bf(v.x * sc); o.y = f2bf(v.y * sc);
  o.z = f2bf(v.z * sc); o.w = f2bf(v.w * sc);
  *(ushort4*)&out[(size_t)row * 1024 + t * 4] = o;
}

// ---------- MFMA flash attention, causal; PAIRED Q-tiles, direct output ----------
// block = (pair u, head); 512 threads = 8 waves, each wave 16 q-rows.
// The block processes Q-tile qt=u then qt=15-u sequentially: per-block work
// = (u+1)+(16-u) = 17 chunks, constant across all 256 blocks (1/CU, no tail).
// Same 8-wave core as the verified split-K version; output written normalized
// (no partials, no merge kernel, no wso traffic).
__global__ __launch_bounds__(512)
void attn_mfma_kernel(const ushort* __restrict__ qh, const ushort* __restrict__ kh,
                      const ushort* __restrict__ vt, ushort* __restrict__ attn_out) {
  __shared__ ushort sQ[128 * 64];
  __shared__ ushort sK[64 * 64];
  __shared__ ushort sV[64 * 64];     // V^T: rows = d, cols = key
  __shared__ ushort sP[8][1024];     // per-wave P [16 qrow][64 key]
  const int h = blockIdx.y;
  const int u = blockIdx.x;          // 0..15
  const int tid = threadIdx.x;
  const int w = tid >> 6, lane = tid & 63;
  const int llo = lane & 15, lhi = lane >> 4;
  const ushort* kg = kh + (size_t)h * 2048 * 64;
  const ushort* vg = vt + (size_t)h * 64 * 2048;

  for (int seg = 0; seg < 2; ++seg) {
    const int qt = seg ? (15 - u) : u;
    const int i0 = qt * 128;
    const ushort* qg = qh + ((size_t)h * 2048 + i0) * 64;

    // stage Q tile: 1024 16B chunks, 2 per thread (wave-uniform bases)
#pragma unroll
    for (int j = 0; j < 2; ++j) {
      const int cb = j * 512 + w * 64;
      const int ch = cb + lane;
      const int row = ch >> 3, c = ch & 7;
      gload_lds16(qg + (size_t)row * 64 + ((c ^ (row & 7)) * 8), &sQ[cb * 8]);
    }
    __syncthreads();
    const int qrow = w * 16 + llo;   // tile-local q row this lane owns (as N col)
    const short8 qf0 = *(const short8*)&sQ[qrow * 64 + ((lhi ^ (qrow & 7)) * 8)];
    const short8 qf1 = *(const short8*)&sQ[qrow * 64 + (((4 + lhi) ^ (qrow & 7)) * 8)];
    const int wmax = i0 + w * 16 + 15;

    float m = -1e30f, lsum = 0.f;
    f32x4 o[4] = {};                 // out frags: col=d=nn*16+llo, row=qrow=lhi*4+r
    const int nch = 2 * qt + 2;
    for (int cb2 = 0; cb2 < nch; ++cb2) {
      const int kb = cb2 * 64;
      __syncthreads();
      {
        const int cb = w * 64;
        const int ch = cb + lane;
        const int row = ch >> 3, c = ch & 7;
        gload_lds16(kg + (size_t)(kb + row) * 64 + ((c ^ (row & 7)) * 8), &sK[cb * 8]);
        gload_lds16(vg + (size_t)row * 2048 + kb + ((c ^ (row & 7)) * 8), &sV[cb * 8]);
      }
      __syncthreads();

      if (kb > wmax) continue;       // wave-uniform causal skip (barriers done)

      f32x4 st[4] = {};
#pragma unroll
      for (int ck = 0; ck < 2; ++ck) {
        const short8 qf = ck ? qf1 : qf0;
#pragma unroll
        for (int f = 0; f < 4; ++f) {
          const int key = f * 16 + llo;
          const short8 kf = *(const short8*)&sK[key * 64 + (((ck * 4 + lhi) ^ (key & 7)) * 8)];
          st[f] = mfma16(kf, qf, st[f]);
        }
      }

      float pv[4][4];
      const bool edge = (kb + 63 > i0 + w * 16);   // boundary chunk needs masking
#pragma unroll
      for (int f = 0; f < 4; ++f)
#pragma unroll
        for (int r = 0; r < 4; ++r) {
          float x = st[f][r] * 0.125f;
          if (edge && (kb - i0 + f * 16 + lhi * 4 + r) > qrow) x = -1e30f;
          pv[f][r] = x;
        }
      float mr = pv[0][0];
#pragma unroll
      for (int f = 0; f < 4; ++f)
#pragma unroll
        for (int r = 0; r < 4; ++r) mr = fmaxf(mr, pv[f][r]);
      mr = fmaxf(mr, __shfl_xor(mr, 16));
      mr = fmaxf(mr, __shfl_xor(mr, 32));
      const float mnew = fmaxf(m, mr);
      const float scale = __expf(m - mnew);
      m = mnew;
      float rs = 0.f;
#pragma unroll
      for (int f = 0; f < 4; ++f)
#pragma unroll
        for (int r = 0; r < 4; ++r) {
          const float p = __expf(pv[f][r] - mnew);
          pv[f][r] = p;
          rs += p;
        }
      rs += __shfl_xor(rs, 16);
      rs += __shfl_xor(rs, 32);
      lsum = lsum * scale + rs;
      float scr[4];
#pragma unroll
      for (int r = 0; r < 4; ++r) scr[r] = __shfl(scale, lhi * 4 + r);
#pragma unroll
      for (int nn = 0; nn < 4; ++nn)
#pragma unroll
        for (int r = 0; r < 4; ++r) o[nn][r] *= scr[r];

      ushort* pw = sP[w];
#pragma unroll
      for (int f = 0; f < 4; ++f) {
        uint2 pk;
        pk.x = (uint)f2bf(pv[f][0]) | ((uint)f2bf(pv[f][1]) << 16);
        pk.y = (uint)f2bf(pv[f][2]) | ((uint)f2bf(pv[f][3]) << 16);
        *(uint2*)&pw[llo * 64 + ((f * 16 + lhi * 4) ^ ((llo & 7) << 3))] = pk;
      }
      const short8 pf0 = *(const short8*)&pw[llo * 64 + ((lhi ^ (llo & 7)) * 8)];
      const short8 pf1 = *(const short8*)&pw[llo * 64 + (((4 + lhi) ^ (llo & 7)) * 8)];

#pragma unroll
      for (int ck = 0; ck < 2; ++ck) {
        const short8 pf = ck ? pf1 : pf0;
#pragma unroll
        for (int nn = 0; nn < 4; ++nn) {
          const int drow = nn * 16 + llo;
          const short8 vf = *(const short8*)&sV[drow * 64 + (((ck * 4 + lhi) ^ (drow & 7)) * 8)];
          o[nn] = mfma16(pf, vf, o[nn]);
        }
      }
    }

    // epilogue: normalize and store bf16
    const float inv = 1.f / lsum;
    float invr[4];
#pragma unroll
    for (int r = 0; r < 4; ++r) invr[r] = __shfl(inv, lhi * 4 + r);
#pragma unroll
    for (int nn = 0; nn < 4; ++nn)
#pragma unroll
      for (int r = 0; r < 4; ++r) {
        const int row = i0 + w * 16 + lhi * 4 + r;
        attn_out[(size_t)row * 1024 + h * 64 + nn * 16 + llo] = f2bf(o[nn][r] * invr[r]);
      }
    __syncthreads();   // all sQ/sK/sV reads done before next seg restages
  }
}

// ---------- 2-phase bf16 MFMA GEMM, BK=64, XOR-swizzled ----------
// C[M][N] = A[M][K] * BT[N][K]^T (+addend). 256 threads = 4 waves (2M x 2N).
// EPI: 0 = f32 store, 1 = f32 addend + store
template <int BM, int BN, int EPI>
__global__ __launch_bounds__(256)
void gemm_bt64_kernel(const ushort* __restrict__ A, const ushort* __restrict__ BT,
                      const float* __restrict__ addend, void* __restrict__ Cout,
                      const int M, const int N, const int K) {
  constexpr int WM = BM / 2, WN = BN / 2;
  constexpr int FM = WM / 16, FN = WN / 16;
  __shared__ ushort sA[BM * 64];
  __shared__ ushort sB[BN * 64];
  const int bm0 = blockIdx.y * BM;
  const int bn0 = blockIdx.x * BN;
  const int tid = threadIdx.x;
  const int wid = tid >> 6, lane = tid & 63;
  const int wr = wid >> 1, wc = wid & 1;
  const int lhi = lane >> 4, llo = lane & 15;
  f32x4 acc[FM][FN] = {};
  for (int kt = 0; kt < K; kt += 64) {
#pragma unroll
    for (int i = 0; i < BM * 8 / 256; ++i) {
      const int cb = i * 256 + wid * 64;        // wave-uniform base chunk
      const int ch = cb + lane;
      const int row = ch >> 3, c = ch & 7;
      gload_lds16(A + (size_t)(bm0 + row) * K + kt + ((c ^ (row & 7)) * 8),
                  sA + (size_t)cb * 8);
    }
#pragma unroll
    for (int i = 0; i < BN * 8 / 256; ++i) {
      const int cb = i * 256 + wid * 64;
      const int ch = cb + lane;
      const int row = ch >> 3, c = ch & 7;
      gload_lds16(BT + (size_t)(bn0 + row) * K + kt + ((c ^ (row & 7)) * 8),
                  sB + (size_t)cb * 8);
    }
    __syncthreads();
    short8 aF[FM][2], bF[FN][2];
#pragma unroll
    for (int mm = 0; mm < FM; ++mm) {
      const int row = wr * WM + mm * 16 + llo;
#pragma unroll
      for (int ks = 0; ks < 2; ++ks)
        aF[mm][ks] = *(const short8*)&sA[row * 64 + (((ks * 4 + lhi) ^ (row & 7)) * 8)];
    }
#pragma unroll
    for (int nn = 0; nn < FN; ++nn) {
      const int row = wc * WN + nn * 16 + llo;
#pragma unroll
      for (int ks = 0; ks < 2; ++ks)
        bF[nn][ks] = *(const short8*)&sB[row * 64 + (((ks * 4 + lhi) ^ (row & 7)) * 8)];
    }
#pragma unroll
    for (int mm = 0; mm < FM; ++mm)
#pragma unroll
      for (int nn = 0; nn < FN; ++nn)
#pragma unroll
        for (int ks = 0; ks < 2; ++ks)
          acc[mm][nn] = mfma16(aF[mm][ks], bF[nn][ks], acc[mm][nn]);
    __syncthreads();
  }
#pragma unroll
  for (int mm = 0; mm < FM; ++mm) {
#pragma unroll
    for (int nn = 0; nn < FN; ++nn) {
      const int col = bn0 + wc * WN + nn * 16 + llo;
#pragma unroll
      for (int r = 0; r < 4; ++r) {
        const int row = bm0 + wr * WM + mm * 16 + lhi * 4 + r;
        float v = acc[mm][nn][r];
        if constexpr (EPI == 1) v += addend[(size_t)row * N + col];
        ((float*)Cout)[(size_t)row * N + col] = v;
      }
    }
  }
}

// ---------- qkv GEMM 128x128 BK=64 with fused RoPE + V^T epilogue ----------
__global__ __launch_bounds__(256)
void gemm_qkv_kernel(const ushort* __restrict__ A, const ushort* __restrict__ BT,
                     const float2* __restrict__ cstab, ushort* __restrict__ qh,
                     ushort* __restrict__ kh, ushort* __restrict__ vt, const int K) {
  constexpr int BM = 128, BN = 128, WM = 64, WN = 64, FM = 4, FN = 4;
  __shared__ ushort sA[BM * 64];
  __shared__ ushort sB[BN * 64];
  const int bm0 = blockIdx.y * BM;
  const int bn0 = blockIdx.x * BN;
  const int tid = threadIdx.x;
  const int wid = tid >> 6, lane = tid & 63;
  const int wr = wid >> 1, wc = wid & 1;
  const int lhi = lane >> 4, llo = lane & 15;
  f32x4 acc[FM][FN] = {};
  for (int kt = 0; kt < K; kt += 64) {
#pragma unroll
    for (int i = 0; i < 4; ++i) {
      const int cb = i * 256 + wid * 64;
      const int ch = cb + lane;
      const int row = ch >> 3, c = ch & 7;
      gload_lds16(A + (size_t)(bm0 + row) * K + kt + ((c ^ (row & 7)) * 8),
                  sA + (size_t)cb * 8);
    }
#pragma unroll
    for (int i = 0; i < 4; ++i) {
      const int cb = i * 256 + wid * 64;
      const int ch = cb + lane;
      const int row = ch >> 3, c = ch & 7;
      gload_lds16(BT + (size_t)(bn0 + row) * K + kt + ((c ^ (row & 7)) * 8),
                  sB + (size_t)cb * 8);
    }
    __syncthreads();
    short8 aF[FM][2], bF[FN][2];
#pragma unroll
    for (int mm = 0; mm < FM; ++mm) {
      const int row = wr * WM + mm * 16 + llo;
#pragma unroll
      for (int ks = 0; ks < 2; ++ks)
        aF[mm][ks] = *(const short8*)&sA[row * 64 + (((ks * 4 + lhi) ^ (row & 7)) * 8)];
    }
#pragma unroll
    for (int nn = 0; nn < FN; ++nn) {
      const int row = wc * WN + nn * 16 + llo;
#pragma unroll
      for (int ks = 0; ks < 2; ++ks)
        bF[nn][ks] = *(const short8*)&sB[row * 64 + (((ks * 4 + lhi) ^ (row & 7)) * 8)];
    }
#pragma unroll
    for (int mm = 0; mm < FM; ++mm)
#pragma unroll
      for (int nn = 0; nn < FN; ++nn)
#pragma unroll
        for (int ks = 0; ks < 2; ++ks)
          acc[mm][nn] = mfma16(aF[mm][ks], bF[nn][ks], acc[mm][nn]);
    __syncthreads();
  }
  // epilogue
#pragma unroll
  for (int mm = 0; mm < FM; ++mm) {
    const int row_base = bm0 + wr * WM + mm * 16 + lhi * 4;
#pragma unroll
    for (int nn = 0; nn < FN; ++nn) {
      const int col = bn0 + wc * WN + nn * 16 + llo;
      const int part = col >> 10;
      const int hcol = col & 1023;
      const int h = hcol >> 6;
      const int d = hcol & 63;
      const int off = d & 31;
      if (part == 2) {
        ushort4 o;
        o.x = f2bf(acc[mm][nn][0]);
        o.y = f2bf(acc[mm][nn][1]);
        o.z = f2bf(acc[mm][nn][2]);
        o.w = f2bf(acc[mm][nn][3]);
        *(ushort4*)&vt[((size_t)h * 64 + d) * 2048 + row_base] = o;
      } else {
#pragma unroll
        for (int r = 0; r < 4; ++r) {
          const int row = row_base + r;
          const float v = acc[mm][nn][r];
          const float pt = acc[mm][nn ^ 2][r];
          const float2 cn = cstab[row * 32 + off];
          const float si = (d < 32) ? -cn.y : cn.y;
          const ushort o = f2bf(cn.x * v + si * pt);
          const size_t ho = ((size_t)h * 2048 + row) * 64 + d;
          if (part == 0) qh[ho] = o; else kh[ho] = o;
        }
      }
    }
  }
}

// ---------- gemm8p: 256x256 BK=32, 3-stage LDS, depth-2 counted-vmcnt ----------
// EPI: 0 = f32 store (vocab), 3 = fused SiLU on interleaved gate/up -> bf16 (up)
template <int EPI>
__global__ __launch_bounds__(512, 2)
void gemm8p_kernel(const ushort* __restrict__ A, const ushort* __restrict__ BT,
                   void* __restrict__ Cout,
                   const int M, const int N, const int K, const int nby) {
  extern __shared__ ushort smem[];   // 3 x 16384 elements
  const int nwg = gridDim.x;
  const int cpx = nwg >> 3;
  int id = blockIdx.x;
  id = (id & 7) * cpx + (id >> 3);   // bijective XCD swizzle (nwg%8==0)
  const int by = id % nby, bx = id / nby;   // by-major: intra-XCD B-panel reuse
  const int bm0 = by * 256, bn0 = bx * 256;
  const int tid = threadIdx.x;
  const int wid = tid >> 6, lane = tid & 63;
  const int wr = wid >> 2, wc = wid & 3;
  const int llo = lane & 15, lhi = lane >> 4;
  const ushort* gA = A + (size_t)bm0 * K;
  const ushort* gB = BT + (size_t)bn0 * K;

  auto stage = [&](ushort* dst, int kt) {
#pragma unroll
    for (int i = 0; i < 2; ++i) {
      const int cb = i * 512 + wid * 64;       // wave-uniform base chunk
      const int ch = cb + lane;
      const int row = ch >> 2, c = ch & 3;
      gload_lds16(gA + (size_t)row * K + kt + ((c ^ ((row >> 1) & 3)) * 8),
                  dst + (size_t)cb * 8);
    }
#pragma unroll
    for (int i = 0; i < 2; ++i) {
      const int cb = i * 512 + wid * 64;
      const int ch = cb + lane;
      const int row = ch >> 2, c = ch & 3;
      gload_lds16(gB + (size_t)row * K + kt + ((c ^ ((row >> 1) & 3)) * 8),
                  dst + 8192 + (size_t)cb * 8);
    }
  };

  f32x4 acc[8][4] = {};
  short8 aF[4], bF[4];

  const int nt = K >> 5;
  stage(smem, 0);
  stage(smem + 16384, 32);
  WAIT_VM4();
  BAR();

  int cs = 0;
  for (int t = 0; t < nt; ++t) {
    ushort* cA = smem + cs * 16384;
    ushort* cB = cA + 8192;
    int ss = cs + 2; if (ss >= 3) ss -= 3;
    const bool pf2 = (t + 2 < nt);
    if (pf2) stage(smem + ss * 16384, (t + 2) * 32);
#pragma unroll
    for (int mm = 0; mm < 4; ++mm) {
      const int row = wr * 128 + mm * 16 + llo;
      aF[mm] = *(const short8*)&cA[row * 32 + ((lhi ^ ((row >> 1) & 3)) * 8)];
    }
#pragma unroll
    for (int nn = 0; nn < 4; ++nn) {
      const int row = wc * 64 + nn * 16 + llo;
      bF[nn] = *(const short8*)&cB[row * 32 + ((lhi ^ ((row >> 1) & 3)) * 8)];
    }
    BAR(); WAIT_LGKM();
    __builtin_amdgcn_s_setprio(1);
#pragma unroll
    for (int mm = 0; mm < 4; ++mm)
#pragma unroll
      for (int nn = 0; nn < 4; ++nn)
        acc[mm][nn] = mfma16(aF[mm], bF[nn], acc[mm][nn]);
    __builtin_amdgcn_s_setprio(0);
    BAR();
#pragma unroll
    for (int mm = 0; mm < 4; ++mm) {
      const int row = wr * 128 + (mm + 4) * 16 + llo;
      aF[mm] = *(const short8*)&cA[row * 32 + ((lhi ^ ((row >> 1) & 3)) * 8)];
    }
    BAR(); WAIT_LGKM();
    __builtin_amdgcn_s_setprio(1);
#pragma unroll
    for (int mm = 0; mm < 4; ++mm)
#pragma unroll
      for (int nn = 0; nn < 4; ++nn)
        acc[mm + 4][nn] = mfma16(aF[mm], bF[nn], acc[mm + 4][nn]);
    __builtin_amdgcn_s_setprio(0);
    if (pf2) { WAIT_VM4(); } else { WAIT_VM0(); }
    BAR();
    ++cs; if (cs == 3) cs = 0;
  }

#pragma unroll
  for (int m = 0; m < 8; ++m) {
#pragma unroll
    for (int n = 0; n < 4; ++n) {
      const int col = bn0 + wc * 64 + n * 16 + llo;
#pragma unroll
      for (int r = 0; r < 4; ++r) {
        const int row = bm0 + wr * 128 + m * 16 + lhi * 4 + r;
        float v = acc[m][n][r];
        if constexpr (EPI == 3) {
          // interleaved upT rows: even col = gate_j, odd col = up_j, j = col>>1
          const float other = __shfl_xor(v, 1);
          if ((llo & 1) == 0) {
            const float gate = v, up = other;
            const float hh = up * gate / (1.f + expf(-gate));
            ((ushort*)Cout)[(size_t)row * (N >> 1) + (col >> 1)] = f2bf(hh);
          }
        } else {
          ((float*)Cout)[(size_t)row * N + col] = v;
        }
      }
    }
  }
}

// ---------- launch ----------
extern "C" void kernel_launch(void* const* d_in, const int* in_sizes, int n_in,
                              void* d_out, int out_size, void* d_ws, size_t ws_size,
                              hipStream_t stream) {
  const int* tokens    = (const int*)d_in[0];
  const float* table   = (const float*)d_in[1];
  const float* qkv_w   = (const float*)d_in[2];
  const float* out_w   = (const float*)d_in[3];
  const float* up_w    = (const float*)d_in[4];
  const float* down_w  = (const float*)d_in[5];
  const float* vocab_w = (const float*)d_in[6];
  float* logits = (float*)d_out;

  constexpr int G8P_LDS = 98304;
  hipFuncSetAttribute(reinterpret_cast<const void*>(&gemm8p_kernel<0>),
                      hipFuncAttributeMaxDynamicSharedMemorySize, G8P_LDS);
  hipFuncSetAttribute(reinterpret_cast<const void*>(&gemm8p_kernel<3>),
                      hipFuncAttributeMaxDynamicSharedMemorySize, G8P_LDS);

  char* p = (char*)d_ws;
  auto alloc = [&](size_t bytes) {
    char* r = p;
    p += (bytes + 255) & ~(size_t)255;
    return r;
  };
  float*  emb    = (float*)alloc(2048ull * 1024 * 4);
  ushort* normed = (ushort*)alloc(2048ull * 1024 * 2);
  float2* cstab  = (float2*)alloc(2048ull * 32 * 8);
  ushort* qhb    = (ushort*)alloc(16ull * 2048 * 64 * 2);
  ushort* khb    = (ushort*)alloc(16ull * 2048 * 64 * 2);
  ushort* vtb    = (ushort*)alloc(16ull * 64 * 2048 * 2);
  ushort* attno  = (ushort*)alloc(2048ull * 1024 * 2);
  ushort* hbuf   = (ushort*)alloc(2048ull * 4096 * 2);
  ushort* qkvT   = (ushort*)alloc(4ull * 3072 * 1024 * 2);
  ushort* outT   = (ushort*)alloc(4ull * 1024 * 1024 * 2);
  ushort* upT    = (ushort*)alloc(4ull * 8192 * 1024 * 2);
  ushort* downT  = (ushort*)alloc(4ull * 1024 * 4096 * 2);
  ushort* vocabT = (ushort*)alloc(32000ull * 1024 * 2);

  // batched weight transposes (z = layer) + RoPE table
  transpose_conv_kernel<<<dim3(3072 / 64, 1024 / 64, 4), 256, 0, stream>>>(
      qkv_w, qkvT, 1024, 3072, 0);
  transpose_conv_kernel<<<dim3(1024 / 64, 1024 / 64, 4), 256, 0, stream>>>(
      out_w, outT, 1024, 1024, 0);
  transpose_conv_kernel<<<dim3(8192 / 64, 1024 / 64, 4), 256, 0, stream>>>(
      up_w, upT, 1024, 8192, 1);
  transpose_conv_kernel<<<dim3(1024 / 64, 4096 / 64, 4), 256, 0, stream>>>(
      down_w, downT, 4096, 1024, 0);
  transpose_conv_kernel<<<dim3(32000 / 64, 1024 / 64, 1), 256, 0, stream>>>(
      vocab_w, vocabT, 1024, 32000, 0);
  sincos_kernel<<<256, 256, 0, stream>>>(cstab);

  embed_norm_kernel<<<2048, 256, 0, stream>>>(tokens, table, emb, normed);

  for (int l = 0; l < 4; ++l) {
    if (l > 0) rmsnorm_kernel<<<2048, 256, 0, stream>>>(emb, normed);
    gemm_qkv_kernel<<<dim3(3072 / 128, 2048 / 128), 256, 0, stream>>>(
        normed, qkvT + (size_t)l * 3072 * 1024, cstab, qhb, khb, vtb, 1024);
    attn_mfma_kernel<<<dim3(16, 16), 512, 0, stream>>>(qhb, khb, vtb, attno);
    gemm_bt64_kernel<64, 128, 1><<<dim3(1024 / 128, 2048 / 64), 256, 0, stream>>>(
        attno, outT + (size_t)l * 1024 * 1024, emb, emb, 2048, 1024, 1024);
    rmsnorm_kernel<<<2048, 256, 0, stream>>>(emb, normed);
    gemm8p_kernel<3><<<(8192 / 256) * (2048 / 256), 512, G8P_LDS, stream>>>(
        normed, upT + (size_t)l * 8192 * 1024, hbuf, 2048, 8192, 1024, 2048 / 256);
    gemm_bt64_kernel<64, 128, 1><<<dim3(1024 / 128, 2048 / 64), 256, 0, stream>>>(
        hbuf, downT + (size_t)l * 1024 * 4096, emb, emb, 2048, 1024, 4096);
  }
  rmsnorm_kernel<<<2048, 256, 0, stream>>>(emb, normed);
  gemm8p_kernel<0><<<(32000 / 256) * (2048 / 256), 512, G8P_LDS, stream>>>(
      normed, vocabT, logits, 2048, 32000, 1024, 2048 / 256);
}

// Round 16
// 1206.743 us; speedup vs baseline: 1.0664x; 1.0664x over previous
//
#include <hip/hip_runtime.h>
#include <hip/hip_bf16.h>

// ---------- types ----------
typedef __attribute__((ext_vector_type(8))) short short8;   // 8 x bf16 bits
typedef __attribute__((ext_vector_type(4))) float f32x4;

__device__ __forceinline__ ushort f2bf(float f) {
  uint32_t u = __float_as_uint(f);
  uint32_t r = (u + 0x7FFFu + ((u >> 16) & 1u)) >> 16;
  return (ushort)r;
}
__device__ __forceinline__ float bf2f(ushort u) {
  return __uint_as_float(((uint32_t)u) << 16);
}

__device__ __forceinline__ void gload_lds16(const ushort* g, ushort* l) {
  __builtin_amdgcn_global_load_lds(
      (const __attribute__((address_space(1))) void*)g,
      (__attribute__((address_space(3))) void*)l, 16, 0, 0);
}

__device__ __forceinline__ f32x4 mfma16(short8 a, short8 b, f32x4 c) {
  return __builtin_amdgcn_mfma_f32_16x16x32_bf16(a, b, c, 0, 0, 0);
}

#define BAR() __builtin_amdgcn_s_barrier()
#define WAIT_LGKM()                                        \
  do {                                                     \
    asm volatile("s_waitcnt lgkmcnt(0)" ::: "memory");     \
    __builtin_amdgcn_sched_barrier(0);                     \
  } while (0)
#define WAIT_VM0()                                         \
  do {                                                     \
    asm volatile("s_waitcnt vmcnt(0)" ::: "memory");       \
    __builtin_amdgcn_sched_barrier(0);                     \
  } while (0)
#define WAIT_VM4()                                         \
  do {                                                     \
    asm volatile("s_waitcnt vmcnt(4)" ::: "memory");       \
    __builtin_amdgcn_sched_barrier(0);                     \
  } while (0)

// ---------- transpose + fp32->bf16 convert: W[K][N] -> WT[p(N)][K] ----------
// 64x64 tiles, float4 loads / ushort4 stores. blockIdx.z = layer.
// mode 0: p(n)=n.  mode 1 (gate/up interleave): p(n)= n<4096 ? 2n : 2(n-4096)+1
__global__ __launch_bounds__(256)
void transpose_conv_kernel(const float* __restrict__ W, ushort* __restrict__ WT,
                           const int K, const int N, const int mode) {
  const size_t lofs = (size_t)blockIdx.z * K * N;
  W += lofs;
  WT += lofs;
  __shared__ float tile[64][65];
  const int n0 = blockIdx.x * 64;
  const int k0 = blockIdx.y * 64;
  const int t = threadIdx.x;
#pragma unroll
  for (int j = 0; j < 4; ++j) {
    const int idx = j * 1024 + t * 4;
    const int kk = idx >> 6, nn = idx & 63;
    *(float4*)&tile[kk][nn] = *(const float4*)&W[(size_t)(k0 + kk) * N + n0 + nn];
  }
  __syncthreads();
#pragma unroll
  for (int j = 0; j < 4; ++j) {
    const int idx = j * 1024 + t * 4;
    const int nn = idx >> 6, kk = idx & 63;
    int rr = n0 + nn;
    if (mode == 1) rr = (rr < 4096) ? (2 * rr) : (2 * (rr - 4096) + 1);
    ushort4 o;
    o.x = f2bf(tile[kk + 0][nn]);
    o.y = f2bf(tile[kk + 1][nn]);
    o.z = f2bf(tile[kk + 2][nn]);
    o.w = f2bf(tile[kk + 3][nn]);
    *(ushort4*)&WT[(size_t)rr * K + k0 + kk] = o;
  }
}

// ---------- RoPE cos/sin table ----------
__global__ __launch_bounds__(256)
void sincos_kernel(float2* __restrict__ cstab) {
  const int idx = blockIdx.x * 256 + threadIdx.x;   // 65536 total
  const int s = idx >> 5, o = idx & 31;
  const float freq = exp2f(-0.41524101186092029f * (float)o);  // 10000^(-o/32)
  const float a = (float)s * freq;
  cstab[idx] = make_float2(cosf(a), sinf(a));
}

// ---------- fused embedding gather + rmsnorm (table row 0 forced to zero) ----------
__global__ __launch_bounds__(256)
void embed_norm_kernel(const int* __restrict__ tokens, const float* __restrict__ table,
                       float* __restrict__ emb, ushort* __restrict__ normed) {
  const int s = blockIdx.x, t = threadIdx.x;
  const int tok = tokens[s];
  float4 v = make_float4(0.f, 0.f, 0.f, 0.f);
  if (tok != 0) v = *(const float4*)&table[(size_t)tok * 1024 + t * 4];
  *(float4*)&emb[(size_t)s * 1024 + t * 4] = v;
  float ss = v.x * v.x + v.y * v.y + v.z * v.z + v.w * v.w;
#pragma unroll
  for (int off = 32; off; off >>= 1) ss += __shfl_xor(ss, off);
  __shared__ float red[4];
  if ((t & 63) == 0) red[t >> 6] = ss;
  __syncthreads();
  const float total = red[0] + red[1] + red[2] + red[3];
  const float sc = rsqrtf(total * (1.f / 1024.f) + 1e-5f);
  ushort4 o;
  o.x = f2bf(v.x * sc); o.y = f2bf(v.y * sc);
  o.z = f2bf(v.z * sc); o.w = f2bf(v.w * sc);
  *(ushort4*)&normed[(size_t)s * 1024 + t * 4] = o;
}

// ---------- rmsnorm over 1024 cols: f32 in -> bf16 out ----------
__global__ __launch_bounds__(256)
void rmsnorm_kernel(const float* __restrict__ x, ushort* __restrict__ out) {
  const int row = blockIdx.x, t = threadIdx.x;
  const float4 v = *(const float4*)&x[(size_t)row * 1024 + t * 4];
  float ss = v.x * v.x + v.y * v.y + v.z * v.z + v.w * v.w;
#pragma unroll
  for (int off = 32; off; off >>= 1) ss += __shfl_xor(ss, off);
  __shared__ float red[4];
  if ((t & 63) == 0) red[t >> 6] = ss;
  __syncthreads();
  const float total = red[0] + red[1] + red[2] + red[3];
  const float sc = rsqrtf(total * (1.f / 1024.f) + 1e-5f);
  ushort4 o;
  o.x = f2bf(v.x * sc); o.y = f2bf(v.y * sc);
  o.z = f2bf(v.z * sc); o.w = f2bf(v.w * sc);
  *(ushort4*)&out[(size_t)row * 1024 + t * 4] = o;
}

// ---------- MFMA flash attention, causal, SPLIT-K over key halves ----------
// block = (128-row Q-tile, key-half, head); 512 threads = 8 waves, each wave
// 16 q-rows. half 0: chunks [0, qt+1); half 1: chunks [qt+1, 2qt+2) -> equal
// work per half. Pairing qt=(h<8)?u:15-u makes co-resident pair work constant.
// Partial (o,m,l) unnormalized to workspace; attn_merge combines halves.
// Grid 512 = 2 blocks/CU: cross-block overlap hides per-chunk staging latency
// (round-15 lesson: 1 block/CU exposes it even when perfectly balanced).
__global__ __launch_bounds__(512)
void attn_mfma_kernel(const ushort* __restrict__ qh, const ushort* __restrict__ kh,
                      const ushort* __restrict__ vt, float* __restrict__ wso,
                      float* __restrict__ wsml) {
  __shared__ ushort sQ[128 * 64];
  __shared__ ushort sK[64 * 64];
  __shared__ ushort sV[64 * 64];     // V^T: rows = d, cols = key
  __shared__ ushort sP[8][1024];     // per-wave P [16 qrow][64 key]
  const int h = blockIdx.y;
  const int u = blockIdx.x;          // 0..31 = (qt_raw, half)
  const int qt_raw = u >> 1, half = u & 1;
  const int qt = (h < 8) ? qt_raw : 15 - qt_raw;   // causal load-balance pairing
  const int i0 = qt * 128;
  const int tid = threadIdx.x;
  const int w = tid >> 6, lane = tid & 63;
  const int llo = lane & 15, lhi = lane >> 4;
  const ushort* qg = qh + ((size_t)h * 2048 + i0) * 64;
  const ushort* kg = kh + (size_t)h * 2048 * 64;
  const ushort* vg = vt + (size_t)h * 64 * 2048;

#pragma unroll
  for (int j = 0; j < 2; ++j) {
    const int cb = j * 512 + w * 64;
    const int ch = cb + lane;
    const int row = ch >> 3, c = ch & 7;
    gload_lds16(qg + (size_t)row * 64 + ((c ^ (row & 7)) * 8), &sQ[cb * 8]);
  }
  __syncthreads();
  const int qrow = w * 16 + llo;     // tile-local q row this lane owns (as N col)
  const short8 qf0 = *(const short8*)&sQ[qrow * 64 + ((lhi ^ (qrow & 7)) * 8)];
  const short8 qf1 = *(const short8*)&sQ[qrow * 64 + (((4 + lhi) ^ (qrow & 7)) * 8)];
  const int wmax = i0 + w * 16 + 15; // wave's last (largest) q row

  float m = -1e30f, lsum = 0.f;
  f32x4 o[4] = {};                   // out frags: col=d=nn*16+llo, row=qrow=lhi*4+r
  const int c0 = half ? (qt + 1) : 0;
  const int c1 = half ? (2 * qt + 2) : (qt + 1);
  for (int cb2 = c0; cb2 < c1; ++cb2) {
    const int kb = cb2 * 64;
    __syncthreads();
    {
      const int cb = w * 64;
      const int ch = cb + lane;
      const int row = ch >> 3, c = ch & 7;
      gload_lds16(kg + (size_t)(kb + row) * 64 + ((c ^ (row & 7)) * 8), &sK[cb * 8]);
      gload_lds16(vg + (size_t)row * 2048 + kb + ((c ^ (row & 7)) * 8), &sV[cb * 8]);
    }
    __syncthreads();

    if (kb > wmax) continue;         // wave-uniform causal skip (barriers done)

    f32x4 st[4] = {};
#pragma unroll
    for (int ck = 0; ck < 2; ++ck) {
      const short8 qf = ck ? qf1 : qf0;
#pragma unroll
      for (int f = 0; f < 4; ++f) {
        const int key = f * 16 + llo;
        const short8 kf = *(const short8*)&sK[key * 64 + (((ck * 4 + lhi) ^ (key & 7)) * 8)];
        st[f] = mfma16(kf, qf, st[f]);
      }
    }

    float pv[4][4];
    const bool edge = (kb + 63 > i0 + w * 16);   // boundary chunk needs masking
#pragma unroll
    for (int f = 0; f < 4; ++f)
#pragma unroll
      for (int r = 0; r < 4; ++r) {
        float x = st[f][r] * 0.125f;
        if (edge && (kb - i0 + f * 16 + lhi * 4 + r) > qrow) x = -1e30f;
        pv[f][r] = x;
      }
    float mr = pv[0][0];
#pragma unroll
    for (int f = 0; f < 4; ++f)
#pragma unroll
      for (int r = 0; r < 4; ++r) mr = fmaxf(mr, pv[f][r]);
    mr = fmaxf(mr, __shfl_xor(mr, 16));
    mr = fmaxf(mr, __shfl_xor(mr, 32));
    const float mnew = fmaxf(m, mr);
    const float scale = __expf(m - mnew);
    m = mnew;
    float rs = 0.f;
#pragma unroll
    for (int f = 0; f < 4; ++f)
#pragma unroll
      for (int r = 0; r < 4; ++r) {
        const float p = __expf(pv[f][r] - mnew);
        pv[f][r] = p;
        rs += p;
      }
    rs += __shfl_xor(rs, 16);
    rs += __shfl_xor(rs, 32);
    lsum = lsum * scale + rs;
    float scr[4];
#pragma unroll
    for (int r = 0; r < 4; ++r) scr[r] = __shfl(scale, lhi * 4 + r);
#pragma unroll
    for (int nn = 0; nn < 4; ++nn)
#pragma unroll
      for (int r = 0; r < 4; ++r) o[nn][r] *= scr[r];

    ushort* pw = sP[w];
#pragma unroll
    for (int f = 0; f < 4; ++f) {
      uint2 pk;
      pk.x = (uint)f2bf(pv[f][0]) | ((uint)f2bf(pv[f][1]) << 16);
      pk.y = (uint)f2bf(pv[f][2]) | ((uint)f2bf(pv[f][3]) << 16);
      *(uint2*)&pw[llo * 64 + ((f * 16 + lhi * 4) ^ ((llo & 7) << 3))] = pk;
    }
    const short8 pf0 = *(const short8*)&pw[llo * 64 + ((lhi ^ (llo & 7)) * 8)];
    const short8 pf1 = *(const short8*)&pw[llo * 64 + (((4 + lhi) ^ (llo & 7)) * 8)];

#pragma unroll
    for (int ck = 0; ck < 2; ++ck) {
      const short8 pf = ck ? pf1 : pf0;
#pragma unroll
      for (int nn = 0; nn < 4; ++nn) {
        const int drow = nn * 16 + llo;
        const short8 vf = *(const short8*)&sV[drow * 64 + (((ck * 4 + lhi) ^ (drow & 7)) * 8)];
        o[nn] = mfma16(pf, vf, o[nn]);
      }
    }
  }

  // partial store (unnormalized): o -> wso[half][h][row][d], (m,l) -> wsml
#pragma unroll
  for (int nn = 0; nn < 4; ++nn)
#pragma unroll
    for (int r = 0; r < 4; ++r) {
      const int row = i0 + w * 16 + lhi * 4 + r;
      wso[((size_t)(half * 16 + h) * 2048 + row) * 64 + nn * 16 + llo] = o[nn][r];
    }
  if (lhi == 0) {
    const int row = i0 + w * 16 + llo;
    *(float2*)&wsml[((size_t)(half * 16 + h) * 2048 + row) * 2] = make_float2(m, lsum);
  }
}

// ---------- merge the two key-half partials -> bf16 attn_out ----------
__global__ __launch_bounds__(256)
void attn_merge_kernel(const float* __restrict__ wso, const float* __restrict__ wsml,
                       ushort* __restrict__ attn_out) {
  const int row = blockIdx.x;
  const int t = threadIdx.x;
  const int h = t >> 4, dg = t & 15;
  const float2 ml1 = *(const float2*)&wsml[((size_t)h * 2048 + row) * 2];
  const float2 ml2 = *(const float2*)&wsml[((size_t)(16 + h) * 2048 + row) * 2];
  const float m = fmaxf(ml1.x, ml2.x);
  const float w1 = __expf(ml1.x - m), w2 = __expf(ml2.x - m);
  const float inv = 1.f / (ml1.y * w1 + ml2.y * w2);
  const float4 o1 = *(const float4*)&wso[((size_t)h * 2048 + row) * 64 + dg * 4];
  const float4 o2 = *(const float4*)&wso[((size_t)(16 + h) * 2048 + row) * 64 + dg * 4];
  ushort4 o;
  o.x = f2bf((o1.x * w1 + o2.x * w2) * inv);
  o.y = f2bf((o1.y * w1 + o2.y * w2) * inv);
  o.z = f2bf((o1.z * w1 + o2.z * w2) * inv);
  o.w = f2bf((o1.w * w1 + o2.w * w2) * inv);
  *(ushort4*)&attn_out[(size_t)row * 1024 + h * 64 + dg * 4] = o;
}

// ---------- 2-phase bf16 MFMA GEMM, BK=64, XOR-swizzled ----------
// C[M][N] = A[M][K] * BT[N][K]^T (+addend). 256 threads = 4 waves (2M x 2N).
// EPI: 0 = f32 store, 1 = f32 addend + store
template <int BM, int BN, int EPI>
__global__ __launch_bounds__(256)
void gemm_bt64_kernel(const ushort* __restrict__ A, const ushort* __restrict__ BT,
                      const float* __restrict__ addend, void* __restrict__ Cout,
                      const int M, const int N, const int K) {
  constexpr int WM = BM / 2, WN = BN / 2;
  constexpr int FM = WM / 16, FN = WN / 16;
  __shared__ ushort sA[BM * 64];
  __shared__ ushort sB[BN * 64];
  const int bm0 = blockIdx.y * BM;
  const int bn0 = blockIdx.x * BN;
  const int tid = threadIdx.x;
  const int wid = tid >> 6, lane = tid & 63;
  const int wr = wid >> 1, wc = wid & 1;
  const int lhi = lane >> 4, llo = lane & 15;
  f32x4 acc[FM][FN] = {};
  for (int kt = 0; kt < K; kt += 64) {
#pragma unroll
    for (int i = 0; i < BM * 8 / 256; ++i) {
      const int cb = i * 256 + wid * 64;        // wave-uniform base chunk
      const int ch = cb + lane;
      const int row = ch >> 3, c = ch & 7;
      gload_lds16(A + (size_t)(bm0 + row) * K + kt + ((c ^ (row & 7)) * 8),
                  sA + (size_t)cb * 8);
    }
#pragma unroll
    for (int i = 0; i < BN * 8 / 256; ++i) {
      const int cb = i * 256 + wid * 64;
      const int ch = cb + lane;
      const int row = ch >> 3, c = ch & 7;
      gload_lds16(BT + (size_t)(bn0 + row) * K + kt + ((c ^ (row & 7)) * 8),
                  sB + (size_t)cb * 8);
    }
    __syncthreads();
    short8 aF[FM][2], bF[FN][2];
#pragma unroll
    for (int mm = 0; mm < FM; ++mm) {
      const int row = wr * WM + mm * 16 + llo;
#pragma unroll
      for (int ks = 0; ks < 2; ++ks)
        aF[mm][ks] = *(const short8*)&sA[row * 64 + (((ks * 4 + lhi) ^ (row & 7)) * 8)];
    }
#pragma unroll
    for (int nn = 0; nn < FN; ++nn) {
      const int row = wc * WN + nn * 16 + llo;
#pragma unroll
      for (int ks = 0; ks < 2; ++ks)
        bF[nn][ks] = *(const short8*)&sB[row * 64 + (((ks * 4 + lhi) ^ (row & 7)) * 8)];
    }
#pragma unroll
    for (int mm = 0; mm < FM; ++mm)
#pragma unroll
      for (int nn = 0; nn < FN; ++nn)
#pragma unroll
        for (int ks = 0; ks < 2; ++ks)
          acc[mm][nn] = mfma16(aF[mm][ks], bF[nn][ks], acc[mm][nn]);
    __syncthreads();
  }
#pragma unroll
  for (int mm = 0; mm < FM; ++mm) {
#pragma unroll
    for (int nn = 0; nn < FN; ++nn) {
      const int col = bn0 + wc * WN + nn * 16 + llo;
#pragma unroll
      for (int r = 0; r < 4; ++r) {
        const int row = bm0 + wr * WM + mm * 16 + lhi * 4 + r;
        float v = acc[mm][nn][r];
        if constexpr (EPI == 1) v += addend[(size_t)row * N + col];
        ((float*)Cout)[(size_t)row * N + col] = v;
      }
    }
  }
}

// ---------- qkv GEMM 128x128 BK=64 with fused RoPE + V^T epilogue ----------
__global__ __launch_bounds__(256)
void gemm_qkv_kernel(const ushort* __restrict__ A, const ushort* __restrict__ BT,
                     const float2* __restrict__ cstab, ushort* __restrict__ qh,
                     ushort* __restrict__ kh, ushort* __restrict__ vt, const int K) {
  constexpr int BM = 128, BN = 128, WM = 64, WN = 64, FM = 4, FN = 4;
  __shared__ ushort sA[BM * 64];
  __shared__ ushort sB[BN * 64];
  const int bm0 = blockIdx.y * BM;
  const int bn0 = blockIdx.x * BN;
  const int tid = threadIdx.x;
  const int wid = tid >> 6, lane = tid & 63;
  const int wr = wid >> 1, wc = wid & 1;
  const int lhi = lane >> 4, llo = lane & 15;
  f32x4 acc[FM][FN] = {};
  for (int kt = 0; kt < K; kt += 64) {
#pragma unroll
    for (int i = 0; i < 4; ++i) {
      const int cb = i * 256 + wid * 64;
      const int ch = cb + lane;
      const int row = ch >> 3, c = ch & 7;
      gload_lds16(A + (size_t)(bm0 + row) * K + kt + ((c ^ (row & 7)) * 8),
                  sA + (size_t)cb * 8);
    }
#pragma unroll
    for (int i = 0; i < 4; ++i) {
      const int cb = i * 256 + wid * 64;
      const int ch = cb + lane;
      const int row = ch >> 3, c = ch & 7;
      gload_lds16(BT + (size_t)(bn0 + row) * K + kt + ((c ^ (row & 7)) * 8),
                  sB + (size_t)cb * 8);
    }
    __syncthreads();
    short8 aF[FM][2], bF[FN][2];
#pragma unroll
    for (int mm = 0; mm < FM; ++mm) {
      const int row = wr * WM + mm * 16 + llo;
#pragma unroll
      for (int ks = 0; ks < 2; ++ks)
        aF[mm][ks] = *(const short8*)&sA[row * 64 + (((ks * 4 + lhi) ^ (row & 7)) * 8)];
    }
#pragma unroll
    for (int nn = 0; nn < FN; ++nn) {
      const int row = wc * WN + nn * 16 + llo;
#pragma unroll
      for (int ks = 0; ks < 2; ++ks)
        bF[nn][ks] = *(const short8*)&sB[row * 64 + (((ks * 4 + lhi) ^ (row & 7)) * 8)];
    }
#pragma unroll
    for (int mm = 0; mm < FM; ++mm)
#pragma unroll
      for (int nn = 0; nn < FN; ++nn)
#pragma unroll
        for (int ks = 0; ks < 2; ++ks)
          acc[mm][nn] = mfma16(aF[mm][ks], bF[nn][ks], acc[mm][nn]);
    __syncthreads();
  }
  // epilogue
#pragma unroll
  for (int mm = 0; mm < FM; ++mm) {
    const int row_base = bm0 + wr * WM + mm * 16 + lhi * 4;
#pragma unroll
    for (int nn = 0; nn < FN; ++nn) {
      const int col = bn0 + wc * WN + nn * 16 + llo;
      const int part = col >> 10;
      const int hcol = col & 1023;
      const int h = hcol >> 6;
      const int d = hcol & 63;
      const int off = d & 31;
      if (part == 2) {
        ushort4 o;
        o.x = f2bf(acc[mm][nn][0]);
        o.y = f2bf(acc[mm][nn][1]);
        o.z = f2bf(acc[mm][nn][2]);
        o.w = f2bf(acc[mm][nn][3]);
        *(ushort4*)&vt[((size_t)h * 64 + d) * 2048 + row_base] = o;
      } else {
#pragma unroll
        for (int r = 0; r < 4; ++r) {
          const int row = row_base + r;
          const float v = acc[mm][nn][r];
          const float pt = acc[mm][nn ^ 2][r];
          const float2 cn = cstab[row * 32 + off];
          const float si = (d < 32) ? -cn.y : cn.y;
          const ushort o = f2bf(cn.x * v + si * pt);
          const size_t ho = ((size_t)h * 2048 + row) * 64 + d;
          if (part == 0) qh[ho] = o; else kh[ho] = o;
        }
      }
    }
  }
}

// ---------- gemm8p: 256x256 BK=32, 3-stage LDS, depth-2 counted-vmcnt ----------
// EPI: 0 = f32 store (vocab), 3 = fused SiLU on interleaved gate/up -> bf16 (up)
template <int EPI>
__global__ __launch_bounds__(512, 2)
void gemm8p_kernel(const ushort* __restrict__ A, const ushort* __restrict__ BT,
                   void* __restrict__ Cout,
                   const int M, const int N, const int K, const int nby) {
  extern __shared__ ushort smem[];   // 3 x 16384 elements
  const int nwg = gridDim.x;
  const int cpx = nwg >> 3;
  int id = blockIdx.x;
  id = (id & 7) * cpx + (id >> 3);   // bijective XCD swizzle (nwg%8==0)
  const int by = id % nby, bx = id / nby;   // by-major: intra-XCD B-panel reuse
  const int bm0 = by * 256, bn0 = bx * 256;
  const int tid = threadIdx.x;
  const int wid = tid >> 6, lane = tid & 63;
  const int wr = wid >> 2, wc = wid & 3;
  const int llo = lane & 15, lhi = lane >> 4;
  const ushort* gA = A + (size_t)bm0 * K;
  const ushort* gB = BT + (size_t)bn0 * K;

  auto stage = [&](ushort* dst, int kt) {
#pragma unroll
    for (int i = 0; i < 2; ++i) {
      const int cb = i * 512 + wid * 64;       // wave-uniform base chunk
      const int ch = cb + lane;
      const int row = ch >> 2, c = ch & 3;
      gload_lds16(gA + (size_t)row * K + kt + ((c ^ ((row >> 1) & 3)) * 8),
                  dst + (size_t)cb * 8);
    }
#pragma unroll
    for (int i = 0; i < 2; ++i) {
      const int cb = i * 512 + wid * 64;
      const int ch = cb + lane;
      const int row = ch >> 2, c = ch & 3;
      gload_lds16(gB + (size_t)row * K + kt + ((c ^ ((row >> 1) & 3)) * 8),
                  dst + 8192 + (size_t)cb * 8);
    }
  };

  f32x4 acc[8][4] = {};
  short8 aF[4], bF[4];

  const int nt = K >> 5;
  stage(smem, 0);
  stage(smem + 16384, 32);
  WAIT_VM4();
  BAR();

  int cs = 0;
  for (int t = 0; t < nt; ++t) {
    ushort* cA = smem + cs * 16384;
    ushort* cB = cA + 8192;
    int ss = cs + 2; if (ss >= 3) ss -= 3;
    const bool pf2 = (t + 2 < nt);
    if (pf2) stage(smem + ss * 16384, (t + 2) * 32);
#pragma unroll
    for (int mm = 0; mm < 4; ++mm) {
      const int row = wr * 128 + mm * 16 + llo;
      aF[mm] = *(const short8*)&cA[row * 32 + ((lhi ^ ((row >> 1) & 3)) * 8)];
    }
#pragma unroll
    for (int nn = 0; nn < 4; ++nn) {
      const int row = wc * 64 + nn * 16 + llo;
      bF[nn] = *(const short8*)&cB[row * 32 + ((lhi ^ ((row >> 1) & 3)) * 8)];
    }
    BAR(); WAIT_LGKM();
    __builtin_amdgcn_s_setprio(1);
#pragma unroll
    for (int mm = 0; mm < 4; ++mm)
#pragma unroll
      for (int nn = 0; nn < 4; ++nn)
        acc[mm][nn] = mfma16(aF[mm], bF[nn], acc[mm][nn]);
    __builtin_amdgcn_s_setprio(0);
    BAR();
#pragma unroll
    for (int mm = 0; mm < 4; ++mm) {
      const int row = wr * 128 + (mm + 4) * 16 + llo;
      aF[mm] = *(const short8*)&cA[row * 32 + ((lhi ^ ((row >> 1) & 3)) * 8)];
    }
    BAR(); WAIT_LGKM();
    __builtin_amdgcn_s_setprio(1);
#pragma unroll
    for (int mm = 0; mm < 4; ++mm)
#pragma unroll
      for (int nn = 0; nn < 4; ++nn)
        acc[mm + 4][nn] = mfma16(aF[mm], bF[nn], acc[mm + 4][nn]);
    __builtin_amdgcn_s_setprio(0);
    if (pf2) { WAIT_VM4(); } else { WAIT_VM0(); }
    BAR();
    ++cs; if (cs == 3) cs = 0;
  }

#pragma unroll
  for (int m = 0; m < 8; ++m) {
#pragma unroll
    for (int n = 0; n < 4; ++n) {
      const int col = bn0 + wc * 64 + n * 16 + llo;
#pragma unroll
      for (int r = 0; r < 4; ++r) {
        const int row = bm0 + wr * 128 + m * 16 + lhi * 4 + r;
        float v = acc[m][n][r];
        if constexpr (EPI == 3) {
          // interleaved upT rows: even col = gate_j, odd col = up_j, j = col>>1
          const float other = __shfl_xor(v, 1);
          if ((llo & 1) == 0) {
            const float gate = v, up = other;
            const float hh = up * gate / (1.f + expf(-gate));
            ((ushort*)Cout)[(size_t)row * (N >> 1) + (col >> 1)] = f2bf(hh);
          }
        } else {
          ((float*)Cout)[(size_t)row * N + col] = v;
        }
      }
    }
  }
}

// ---------- launch ----------
extern "C" void kernel_launch(void* const* d_in, const int* in_sizes, int n_in,
                              void* d_out, int out_size, void* d_ws, size_t ws_size,
                              hipStream_t stream) {
  const int* tokens    = (const int*)d_in[0];
  const float* table   = (const float*)d_in[1];
  const float* qkv_w   = (const float*)d_in[2];
  const float* out_w   = (const float*)d_in[3];
  const float* up_w    = (const float*)d_in[4];
  const float* down_w  = (const float*)d_in[5];
  const float* vocab_w = (const float*)d_in[6];
  float* logits = (float*)d_out;

  constexpr int G8P_LDS = 98304;
  hipFuncSetAttribute(reinterpret_cast<const void*>(&gemm8p_kernel<0>),
                      hipFuncAttributeMaxDynamicSharedMemorySize, G8P_LDS);
  hipFuncSetAttribute(reinterpret_cast<const void*>(&gemm8p_kernel<3>),
                      hipFuncAttributeMaxDynamicSharedMemorySize, G8P_LDS);

  char* p = (char*)d_ws;
  auto alloc = [&](size_t bytes) {
    char* r = p;
    p += (bytes + 255) & ~(size_t)255;
    return r;
  };
  float*  emb    = (float*)alloc(2048ull * 1024 * 4);
  ushort* normed = (ushort*)alloc(2048ull * 1024 * 2);
  float2* cstab  = (float2*)alloc(2048ull * 32 * 8);
  ushort* qhb    = (ushort*)alloc(16ull * 2048 * 64 * 2);
  ushort* khb    = (ushort*)alloc(16ull * 2048 * 64 * 2);
  ushort* vtb    = (ushort*)alloc(16ull * 64 * 2048 * 2);
  ushort* attno  = (ushort*)alloc(2048ull * 1024 * 2);
  float*  wso    = (float*)alloc(2ull * 16 * 2048 * 64 * 4);
  float*  wsml   = (float*)alloc(2ull * 16 * 2048 * 2 * 4);
  ushort* hbuf   = (ushort*)alloc(2048ull * 4096 * 2);
  ushort* qkvT   = (ushort*)alloc(4ull * 3072 * 1024 * 2);
  ushort* outT   = (ushort*)alloc(4ull * 1024 * 1024 * 2);
  ushort* upT    = (ushort*)alloc(4ull * 8192 * 1024 * 2);
  ushort* downT  = (ushort*)alloc(4ull * 1024 * 4096 * 2);
  ushort* vocabT = (ushort*)alloc(32000ull * 1024 * 2);

  // batched weight transposes (z = layer) + RoPE table
  transpose_conv_kernel<<<dim3(3072 / 64, 1024 / 64, 4), 256, 0, stream>>>(
      qkv_w, qkvT, 1024, 3072, 0);
  transpose_conv_kernel<<<dim3(1024 / 64, 1024 / 64, 4), 256, 0, stream>>>(
      out_w, outT, 1024, 1024, 0);
  transpose_conv_kernel<<<dim3(8192 / 64, 1024 / 64, 4), 256, 0, stream>>>(
      up_w, upT, 1024, 8192, 1);
  transpose_conv_kernel<<<dim3(1024 / 64, 4096 / 64, 4), 256, 0, stream>>>(
      down_w, downT, 4096, 1024, 0);
  transpose_conv_kernel<<<dim3(32000 / 64, 1024 / 64, 1), 256, 0, stream>>>(
      vocab_w, vocabT, 1024, 32000, 0);
  sincos_kernel<<<256, 256, 0, stream>>>(cstab);

  embed_norm_kernel<<<2048, 256, 0, stream>>>(tokens, table, emb, normed);

  for (int l = 0; l < 4; ++l) {
    if (l > 0) rmsnorm_kernel<<<2048, 256, 0, stream>>>(emb, normed);
    gemm_qkv_kernel<<<dim3(3072 / 128, 2048 / 128), 256, 0, stream>>>(
        normed, qkvT + (size_t)l * 3072 * 1024, cstab, qhb, khb, vtb, 1024);
    attn_mfma_kernel<<<dim3(32, 16), 512, 0, stream>>>(qhb, khb, vtb, wso, wsml);
    attn_merge_kernel<<<2048, 256, 0, stream>>>(wso, wsml, attno);
    gemm_bt64_kernel<64, 128, 1><<<dim3(1024 / 128, 2048 / 64), 256, 0, stream>>>(
        attno, outT + (size_t)l * 1024 * 1024, emb, emb, 2048, 1024, 1024);
    rmsnorm_kernel<<<2048, 256, 0, stream>>>(emb, normed);
    gemm8p_kernel<3><<<(8192 / 256) * (2048 / 256), 512, G8P_LDS, stream>>>(
        normed, upT + (size_t)l * 8192 * 1024, hbuf, 2048, 8192, 1024, 2048 / 256);
    gemm_bt64_kernel<64, 128, 1><<<dim3(1024 / 128, 2048 / 64), 256, 0, stream>>>(
        hbuf, downT + (size_t)l * 1024 * 4096, emb, emb, 2048, 1024, 4096);
  }
  rmsnorm_kernel<<<2048, 256, 0, stream>>>(emb, normed);
  gemm8p_kernel<0><<<(32000 / 256) * (2048 / 256), 512, G8P_LDS, stream>>>(
      normed, vocabT, logits, 2048, 32000, 1024, 2048 / 256);
}

// Round 17
// 1191.292 us; speedup vs baseline: 1.0803x; 1.0130x over previous
//
#include <hip/hip_runtime.h>
#include <hip/hip_bf16.h>

// ---------- types ----------
typedef __attribute__((ext_vector_type(8))) short short8;   // 8 x bf16 bits
typedef __attribute__((ext_vector_type(4))) float f32x4;

__device__ __forceinline__ ushort f2bf(float f) {
  uint32_t u = __float_as_uint(f);
  uint32_t r = (u + 0x7FFFu + ((u >> 16) & 1u)) >> 16;
  return (ushort)r;
}
__device__ __forceinline__ float bf2f(ushort u) {
  return __uint_as_float(((uint32_t)u) << 16);
}

__device__ __forceinline__ void gload_lds16(const ushort* g, ushort* l) {
  __builtin_amdgcn_global_load_lds(
      (const __attribute__((address_space(1))) void*)g,
      (__attribute__((address_space(3))) void*)l, 16, 0, 0);
}

__device__ __forceinline__ f32x4 mfma16(short8 a, short8 b, f32x4 c) {
  return __builtin_amdgcn_mfma_f32_16x16x32_bf16(a, b, c, 0, 0, 0);
}

#define BAR() __builtin_amdgcn_s_barrier()
#define WAIT_LGKM()                                        \
  do {                                                     \
    asm volatile("s_waitcnt lgkmcnt(0)" ::: "memory");     \
    __builtin_amdgcn_sched_barrier(0);                     \
  } while (0)
#define WAIT_VM0()                                         \
  do {                                                     \
    asm volatile("s_waitcnt vmcnt(0)" ::: "memory");       \
    __builtin_amdgcn_sched_barrier(0);                     \
  } while (0)
#define WAIT_VM4()                                         \
  do {                                                     \
    asm volatile("s_waitcnt vmcnt(4)" ::: "memory");       \
    __builtin_amdgcn_sched_barrier(0);                     \
  } while (0)

// ---------- transpose + fp32->bf16 convert: W[K][N] -> WT[p(N)][K] ----------
// 64x64 tiles, float4 loads / ushort4 stores. blockIdx.z = layer.
// mode 0: p(n)=n.  mode 1 (gate/up interleave): p(n)= n<4096 ? 2n : 2(n-4096)+1
__global__ __launch_bounds__(256)
void transpose_conv_kernel(const float* __restrict__ W, ushort* __restrict__ WT,
                           const int K, const int N, const int mode) {
  const size_t lofs = (size_t)blockIdx.z * K * N;
  W += lofs;
  WT += lofs;
  __shared__ float tile[64][65];
  const int n0 = blockIdx.x * 64;
  const int k0 = blockIdx.y * 64;
  const int t = threadIdx.x;
#pragma unroll
  for (int j = 0; j < 4; ++j) {
    const int idx = j * 1024 + t * 4;
    const int kk = idx >> 6, nn = idx & 63;
    *(float4*)&tile[kk][nn] = *(const float4*)&W[(size_t)(k0 + kk) * N + n0 + nn];
  }
  __syncthreads();
#pragma unroll
  for (int j = 0; j < 4; ++j) {
    const int idx = j * 1024 + t * 4;
    const int nn = idx >> 6, kk = idx & 63;
    int rr = n0 + nn;
    if (mode == 1) rr = (rr < 4096) ? (2 * rr) : (2 * (rr - 4096) + 1);
    ushort4 o;
    o.x = f2bf(tile[kk + 0][nn]);
    o.y = f2bf(tile[kk + 1][nn]);
    o.z = f2bf(tile[kk + 2][nn]);
    o.w = f2bf(tile[kk + 3][nn]);
    *(ushort4*)&WT[(size_t)rr * K + k0 + kk] = o;
  }
}

// ---------- RoPE cos/sin table ----------
__global__ __launch_bounds__(256)
void sincos_kernel(float2* __restrict__ cstab) {
  const int idx = blockIdx.x * 256 + threadIdx.x;   // 65536 total
  const int s = idx >> 5, o = idx & 31;
  const float freq = exp2f(-0.41524101186092029f * (float)o);  // 10000^(-o/32)
  const float a = (float)s * freq;
  cstab[idx] = make_float2(cosf(a), sinf(a));
}

// ---------- fused embedding gather + rmsnorm (table row 0 forced to zero) ----------
__global__ __launch_bounds__(256)
void embed_norm_kernel(const int* __restrict__ tokens, const float* __restrict__ table,
                       float* __restrict__ emb, ushort* __restrict__ normed) {
  const int s = blockIdx.x, t = threadIdx.x;
  const int tok = tokens[s];
  float4 v = make_float4(0.f, 0.f, 0.f, 0.f);
  if (tok != 0) v = *(const float4*)&table[(size_t)tok * 1024 + t * 4];
  *(float4*)&emb[(size_t)s * 1024 + t * 4] = v;
  float ss = v.x * v.x + v.y * v.y + v.z * v.z + v.w * v.w;
#pragma unroll
  for (int off = 32; off; off >>= 1) ss += __shfl_xor(ss, off);
  __shared__ float red[4];
  if ((t & 63) == 0) red[t >> 6] = ss;
  __syncthreads();
  const float total = red[0] + red[1] + red[2] + red[3];
  const float sc = rsqrtf(total * (1.f / 1024.f) + 1e-5f);
  ushort4 o;
  o.x = f2bf(v.x * sc); o.y = f2bf(v.y * sc);
  o.z = f2bf(v.z * sc); o.w = f2bf(v.w * sc);
  *(ushort4*)&normed[(size_t)s * 1024 + t * 4] = o;
}

// ---------- rmsnorm over 1024 cols: f32 in -> bf16 out ----------
__global__ __launch_bounds__(256)
void rmsnorm_kernel(const float* __restrict__ x, ushort* __restrict__ out) {
  const int row = blockIdx.x, t = threadIdx.x;
  const float4 v = *(const float4*)&x[(size_t)row * 1024 + t * 4];
  float ss = v.x * v.x + v.y * v.y + v.z * v.z + v.w * v.w;
#pragma unroll
  for (int off = 32; off; off >>= 1) ss += __shfl_xor(ss, off);
  __shared__ float red[4];
  if ((t & 63) == 0) red[t >> 6] = ss;
  __syncthreads();
  const float total = red[0] + red[1] + red[2] + red[3];
  const float sc = rsqrtf(total * (1.f / 1024.f) + 1e-5f);
  ushort4 o;
  o.x = f2bf(v.x * sc); o.y = f2bf(v.y * sc);
  o.z = f2bf(v.z * sc); o.w = f2bf(v.w * sc);
  *(ushort4*)&out[(size_t)row * 1024 + t * 4] = o;
}

// ---------- MFMA flash attention, causal, SPLIT-K, double-buffered K/V ----------
// block = (128-row Q-tile, key-half, head); 512 threads = 8 waves, each wave
// 16 q-rows. half 0: chunks [0, qt+1); half 1: chunks [qt+1, 2qt+2) -> equal
// work per half. Pairing qt=(h<8)?u:15-u makes co-resident pair work constant.
// K/V double-buffered: chunk t+1's global_load_lds issued BEFORE chunk t's
// compute; the single __syncthreads() per chunk (implicit vmcnt drain) both
// lands buf^1 and fences reads of buf before the next iteration overwrites it.
// Partial (o,m,l) unnormalized to workspace; attn_merge combines halves.
__global__ __launch_bounds__(512)
void attn_mfma_kernel(const ushort* __restrict__ qh, const ushort* __restrict__ kh,
                      const ushort* __restrict__ vt, float* __restrict__ wso,
                      float* __restrict__ wsml) {
  __shared__ ushort sQ[128 * 64];
  __shared__ ushort sK[2][64 * 64];
  __shared__ ushort sV[2][64 * 64];  // V^T: rows = d, cols = key
  __shared__ ushort sP[8][1024];     // per-wave P [16 qrow][64 key]
  const int h = blockIdx.y;
  const int u = blockIdx.x;          // 0..31 = (qt_raw, half)
  const int qt_raw = u >> 1, half = u & 1;
  const int qt = (h < 8) ? qt_raw : 15 - qt_raw;   // causal load-balance pairing
  const int i0 = qt * 128;
  const int tid = threadIdx.x;
  const int w = tid >> 6, lane = tid & 63;
  const int llo = lane & 15, lhi = lane >> 4;
  const ushort* qg = qh + ((size_t)h * 2048 + i0) * 64;
  const ushort* kg = kh + (size_t)h * 2048 * 64;
  const ushort* vg = vt + (size_t)h * 64 * 2048;

  // per-wave 16B-chunk coords for K/V staging (one 64-chunk region per wave)
  const int scb = w * 64;
  const int sch = scb + lane;
  const int srow = sch >> 3, sc = sch & 7;
  auto stage_kv = [&](int kb, int b) {
    gload_lds16(kg + (size_t)(kb + srow) * 64 + ((sc ^ (srow & 7)) * 8),
                &sK[b][scb * 8]);
    gload_lds16(vg + (size_t)srow * 2048 + kb + ((sc ^ (srow & 7)) * 8),
                &sV[b][scb * 8]);
  };

  const int c0 = half ? (qt + 1) : 0;
  const int c1 = half ? (2 * qt + 2) : (qt + 1);

  // prologue: stage Q tile + first K/V chunk; one barrier drains both
#pragma unroll
  for (int j = 0; j < 2; ++j) {
    const int cb = j * 512 + w * 64;
    const int ch = cb + lane;
    const int row = ch >> 3, c = ch & 7;
    gload_lds16(qg + (size_t)row * 64 + ((c ^ (row & 7)) * 8), &sQ[cb * 8]);
  }
  stage_kv(c0 * 64, 0);
  __syncthreads();
  const int qrow = w * 16 + llo;     // tile-local q row this lane owns (as N col)
  const short8 qf0 = *(const short8*)&sQ[qrow * 64 + ((lhi ^ (qrow & 7)) * 8)];
  const short8 qf1 = *(const short8*)&sQ[qrow * 64 + (((4 + lhi) ^ (qrow & 7)) * 8)];
  const int wmax = i0 + w * 16 + 15; // wave's last (largest) q row

  float m = -1e30f, lsum = 0.f;
  f32x4 o[4] = {};                   // out frags: col=d=nn*16+llo, row=qrow=lhi*4+r
  int bufc = 0;
  for (int cb2 = c0; cb2 < c1; ++cb2) {
    const int kb = cb2 * 64;
    if (cb2 + 1 < c1) stage_kv((cb2 + 1) * 64, bufc ^ 1);   // issue next early

    if (kb <= wmax) {                // wave-uniform causal skip
      f32x4 st[4] = {};
#pragma unroll
      for (int ck = 0; ck < 2; ++ck) {
        const short8 qf = ck ? qf1 : qf0;
#pragma unroll
        for (int f = 0; f < 4; ++f) {
          const int key = f * 16 + llo;
          const short8 kf = *(const short8*)&sK[bufc][key * 64 + (((ck * 4 + lhi) ^ (key & 7)) * 8)];
          st[f] = mfma16(kf, qf, st[f]);
        }
      }

      float pv[4][4];
      const bool edge = (kb + 63 > i0 + w * 16);   // boundary chunk needs masking
#pragma unroll
      for (int f = 0; f < 4; ++f)
#pragma unroll
        for (int r = 0; r < 4; ++r) {
          float x = st[f][r] * 0.125f;
          if (edge && (kb - i0 + f * 16 + lhi * 4 + r) > qrow) x = -1e30f;
          pv[f][r] = x;
        }
      float mr = pv[0][0];
#pragma unroll
      for (int f = 0; f < 4; ++f)
#pragma unroll
        for (int r = 0; r < 4; ++r) mr = fmaxf(mr, pv[f][r]);
      mr = fmaxf(mr, __shfl_xor(mr, 16));
      mr = fmaxf(mr, __shfl_xor(mr, 32));
      const float mnew = fmaxf(m, mr);
      const float scale = __expf(m - mnew);
      m = mnew;
      float rs = 0.f;
#pragma unroll
      for (int f = 0; f < 4; ++f)
#pragma unroll
        for (int r = 0; r < 4; ++r) {
          const float p = __expf(pv[f][r] - mnew);
          pv[f][r] = p;
          rs += p;
        }
      rs += __shfl_xor(rs, 16);
      rs += __shfl_xor(rs, 32);
      lsum = lsum * scale + rs;
      float scr[4];
#pragma unroll
      for (int r = 0; r < 4; ++r) scr[r] = __shfl(scale, lhi * 4 + r);
#pragma unroll
      for (int nn = 0; nn < 4; ++nn)
#pragma unroll
        for (int r = 0; r < 4; ++r) o[nn][r] *= scr[r];

      ushort* pw = sP[w];
#pragma unroll
      for (int f = 0; f < 4; ++f) {
        uint2 pk;
        pk.x = (uint)f2bf(pv[f][0]) | ((uint)f2bf(pv[f][1]) << 16);
        pk.y = (uint)f2bf(pv[f][2]) | ((uint)f2bf(pv[f][3]) << 16);
        *(uint2*)&pw[llo * 64 + ((f * 16 + lhi * 4) ^ ((llo & 7) << 3))] = pk;
      }
      const short8 pf0 = *(const short8*)&pw[llo * 64 + ((lhi ^ (llo & 7)) * 8)];
      const short8 pf1 = *(const short8*)&pw[llo * 64 + (((4 + lhi) ^ (llo & 7)) * 8)];

#pragma unroll
      for (int ck = 0; ck < 2; ++ck) {
        const short8 pf = ck ? pf1 : pf0;
#pragma unroll
        for (int nn = 0; nn < 4; ++nn) {
          const int drow = nn * 16 + llo;
          const short8 vf = *(const short8*)&sV[bufc][drow * 64 + (((ck * 4 + lhi) ^ (drow & 7)) * 8)];
          o[nn] = mfma16(pf, vf, o[nn]);
        }
      }
    }

    __syncthreads();   // drains vmcnt (buf^1 landed) + fences reads of bufc
    bufc ^= 1;
  }

  // partial store (unnormalized): o -> wso[half][h][row][d], (m,l) -> wsml
#pragma unroll
  for (int nn = 0; nn < 4; ++nn)
#pragma unroll
    for (int r = 0; r < 4; ++r) {
      const int row = i0 + w * 16 + lhi * 4 + r;
      wso[((size_t)(half * 16 + h) * 2048 + row) * 64 + nn * 16 + llo] = o[nn][r];
    }
  if (lhi == 0) {
    const int row = i0 + w * 16 + llo;
    *(float2*)&wsml[((size_t)(half * 16 + h) * 2048 + row) * 2] = make_float2(m, lsum);
  }
}

// ---------- merge the two key-half partials -> bf16 attn_out ----------
__global__ __launch_bounds__(256)
void attn_merge_kernel(const float* __restrict__ wso, const float* __restrict__ wsml,
                       ushort* __restrict__ attn_out) {
  const int row = blockIdx.x;
  const int t = threadIdx.x;
  const int h = t >> 4, dg = t & 15;
  const float2 ml1 = *(const float2*)&wsml[((size_t)h * 2048 + row) * 2];
  const float2 ml2 = *(const float2*)&wsml[((size_t)(16 + h) * 2048 + row) * 2];
  const float m = fmaxf(ml1.x, ml2.x);
  const float w1 = __expf(ml1.x - m), w2 = __expf(ml2.x - m);
  const float inv = 1.f / (ml1.y * w1 + ml2.y * w2);
  const float4 o1 = *(const float4*)&wso[((size_t)h * 2048 + row) * 64 + dg * 4];
  const float4 o2 = *(const float4*)&wso[((size_t)(16 + h) * 2048 + row) * 64 + dg * 4];
  ushort4 o;
  o.x = f2bf((o1.x * w1 + o2.x * w2) * inv);
  o.y = f2bf((o1.y * w1 + o2.y * w2) * inv);
  o.z = f2bf((o1.z * w1 + o2.z * w2) * inv);
  o.w = f2bf((o1.w * w1 + o2.w * w2) * inv);
  *(ushort4*)&attn_out[(size_t)row * 1024 + h * 64 + dg * 4] = o;
}

// ---------- 2-phase bf16 MFMA GEMM, BK=64, XOR-swizzled ----------
// C[M][N] = A[M][K] * BT[N][K]^T (+addend). 256 threads = 4 waves (2M x 2N).
// EPI: 0 = f32 store, 1 = f32 addend + store
template <int BM, int BN, int EPI>
__global__ __launch_bounds__(256)
void gemm_bt64_kernel(const ushort* __restrict__ A, const ushort* __restrict__ BT,
                      const float* __restrict__ addend, void* __restrict__ Cout,
                      const int M, const int N, const int K) {
  constexpr int WM = BM / 2, WN = BN / 2;
  constexpr int FM = WM / 16, FN = WN / 16;
  __shared__ ushort sA[BM * 64];
  __shared__ ushort sB[BN * 64];
  const int bm0 = blockIdx.y * BM;
  const int bn0 = blockIdx.x * BN;
  const int tid = threadIdx.x;
  const int wid = tid >> 6, lane = tid & 63;
  const int wr = wid >> 1, wc = wid & 1;
  const int lhi = lane >> 4, llo = lane & 15;
  f32x4 acc[FM][FN] = {};
  for (int kt = 0; kt < K; kt += 64) {
#pragma unroll
    for (int i = 0; i < BM * 8 / 256; ++i) {
      const int cb = i * 256 + wid * 64;        // wave-uniform base chunk
      const int ch = cb + lane;
      const int row = ch >> 3, c = ch & 7;
      gload_lds16(A + (size_t)(bm0 + row) * K + kt + ((c ^ (row & 7)) * 8),
                  sA + (size_t)cb * 8);
    }
#pragma unroll
    for (int i = 0; i < BN * 8 / 256; ++i) {
      const int cb = i * 256 + wid * 64;
      const int ch = cb + lane;
      const int row = ch >> 3, c = ch & 7;
      gload_lds16(BT + (size_t)(bn0 + row) * K + kt + ((c ^ (row & 7)) * 8),
                  sB + (size_t)cb * 8);
    }
    __syncthreads();
    short8 aF[FM][2], bF[FN][2];
#pragma unroll
    for (int mm = 0; mm < FM; ++mm) {
      const int row = wr * WM + mm * 16 + llo;
#pragma unroll
      for (int ks = 0; ks < 2; ++ks)
        aF[mm][ks] = *(const short8*)&sA[row * 64 + (((ks * 4 + lhi) ^ (row & 7)) * 8)];
    }
#pragma unroll
    for (int nn = 0; nn < FN; ++nn) {
      const int row = wc * WN + nn * 16 + llo;
#pragma unroll
      for (int ks = 0; ks < 2; ++ks)
        bF[nn][ks] = *(const short8*)&sB[row * 64 + (((ks * 4 + lhi) ^ (row & 7)) * 8)];
    }
#pragma unroll
    for (int mm = 0; mm < FM; ++mm)
#pragma unroll
      for (int nn = 0; nn < FN; ++nn)
#pragma unroll
        for (int ks = 0; ks < 2; ++ks)
          acc[mm][nn] = mfma16(aF[mm][ks], bF[nn][ks], acc[mm][nn]);
    __syncthreads();
  }
#pragma unroll
  for (int mm = 0; mm < FM; ++mm) {
#pragma unroll
    for (int nn = 0; nn < FN; ++nn) {
      const int col = bn0 + wc * WN + nn * 16 + llo;
#pragma unroll
      for (int r = 0; r < 4; ++r) {
        const int row = bm0 + wr * WM + mm * 16 + lhi * 4 + r;
        float v = acc[mm][nn][r];
        if constexpr (EPI == 1) v += addend[(size_t)row * N + col];
        ((float*)Cout)[(size_t)row * N + col] = v;
      }
    }
  }
}

// ---------- qkv GEMM 128x128 BK=64 with fused RoPE + V^T epilogue ----------
__global__ __launch_bounds__(256)
void gemm_qkv_kernel(const ushort* __restrict__ A, const ushort* __restrict__ BT,
                     const float2* __restrict__ cstab, ushort* __restrict__ qh,
                     ushort* __restrict__ kh, ushort* __restrict__ vt, const int K) {
  constexpr int BM = 128, BN = 128, WM = 64, WN = 64, FM = 4, FN = 4;
  __shared__ ushort sA[BM * 64];
  __shared__ ushort sB[BN * 64];
  const int bm0 = blockIdx.y * BM;
  const int bn0 = blockIdx.x * BN;
  const int tid = threadIdx.x;
  const int wid = tid >> 6, lane = tid & 63;
  const int wr = wid >> 1, wc = wid & 1;
  const int lhi = lane >> 4, llo = lane & 15;
  f32x4 acc[FM][FN] = {};
  for (int kt = 0; kt < K; kt += 64) {
#pragma unroll
    for (int i = 0; i < 4; ++i) {
      const int cb = i * 256 + wid * 64;
      const int ch = cb + lane;
      const int row = ch >> 3, c = ch & 7;
      gload_lds16(A + (size_t)(bm0 + row) * K + kt + ((c ^ (row & 7)) * 8),
                  sA + (size_t)cb * 8);
    }
#pragma unroll
    for (int i = 0; i < 4; ++i) {
      const int cb = i * 256 + wid * 64;
      const int ch = cb + lane;
      const int row = ch >> 3, c = ch & 7;
      gload_lds16(BT + (size_t)(bn0 + row) * K + kt + ((c ^ (row & 7)) * 8),
                  sB + (size_t)cb * 8);
    }
    __syncthreads();
    short8 aF[FM][2], bF[FN][2];
#pragma unroll
    for (int mm = 0; mm < FM; ++mm) {
      const int row = wr * WM + mm * 16 + llo;
#pragma unroll
      for (int ks = 0; ks < 2; ++ks)
        aF[mm][ks] = *(const short8*)&sA[row * 64 + (((ks * 4 + lhi) ^ (row & 7)) * 8)];
    }
#pragma unroll
    for (int nn = 0; nn < FN; ++nn) {
      const int row = wc * WN + nn * 16 + llo;
#pragma unroll
      for (int ks = 0; ks < 2; ++ks)
        bF[nn][ks] = *(const short8*)&sB[row * 64 + (((ks * 4 + lhi) ^ (row & 7)) * 8)];
    }
#pragma unroll
    for (int mm = 0; mm < FM; ++mm)
#pragma unroll
      for (int nn = 0; nn < FN; ++nn)
#pragma unroll
        for (int ks = 0; ks < 2; ++ks)
          acc[mm][nn] = mfma16(aF[mm][ks], bF[nn][ks], acc[mm][nn]);
    __syncthreads();
  }
  // epilogue
#pragma unroll
  for (int mm = 0; mm < FM; ++mm) {
    const int row_base = bm0 + wr * WM + mm * 16 + lhi * 4;
#pragma unroll
    for (int nn = 0; nn < FN; ++nn) {
      const int col = bn0 + wc * WN + nn * 16 + llo;
      const int part = col >> 10;
      const int hcol = col & 1023;
      const int h = hcol >> 6;
      const int d = hcol & 63;
      const int off = d & 31;
      if (part == 2) {
        ushort4 o;
        o.x = f2bf(acc[mm][nn][0]);
        o.y = f2bf(acc[mm][nn][1]);
        o.z = f2bf(acc[mm][nn][2]);
        o.w = f2bf(acc[mm][nn][3]);
        *(ushort4*)&vt[((size_t)h * 64 + d) * 2048 + row_base] = o;
      } else {
#pragma unroll
        for (int r = 0; r < 4; ++r) {
          const int row = row_base + r;
          const float v = acc[mm][nn][r];
          const float pt = acc[mm][nn ^ 2][r];
          const float2 cn = cstab[row * 32 + off];
          const float si = (d < 32) ? -cn.y : cn.y;
          const ushort o = f2bf(cn.x * v + si * pt);
          const size_t ho = ((size_t)h * 2048 + row) * 64 + d;
          if (part == 0) qh[ho] = o; else kh[ho] = o;
        }
      }
    }
  }
}

// ---------- gemm8p: 256x256 BK=32, 3-stage LDS, depth-2 counted-vmcnt ----------
// EPI: 0 = f32 store (vocab), 3 = fused SiLU on interleaved gate/up -> bf16 (up)
template <int EPI>
__global__ __launch_bounds__(512, 2)
void gemm8p_kernel(const ushort* __restrict__ A, const ushort* __restrict__ BT,
                   void* __restrict__ Cout,
                   const int M, const int N, const int K, const int nby) {
  extern __shared__ ushort smem[];   // 3 x 16384 elements
  const int nwg = gridDim.x;
  const int cpx = nwg >> 3;
  int id = blockIdx.x;
  id = (id & 7) * cpx + (id >> 3);   // bijective XCD swizzle (nwg%8==0)
  const int by = id % nby, bx = id / nby;   // by-major: intra-XCD B-panel reuse
  const int bm0 = by * 256, bn0 = bx * 256;
  const int tid = threadIdx.x;
  const int wid = tid >> 6, lane = tid & 63;
  const int wr = wid >> 2, wc = wid & 3;
  const int llo = lane & 15, lhi = lane >> 4;
  const ushort* gA = A + (size_t)bm0 * K;
  const ushort* gB = BT + (size_t)bn0 * K;

  auto stage = [&](ushort* dst, int kt) {
#pragma unroll
    for (int i = 0; i < 2; ++i) {
      const int cb = i * 512 + wid * 64;       // wave-uniform base chunk
      const int ch = cb + lane;
      const int row = ch >> 2, c = ch & 3;
      gload_lds16(gA + (size_t)row * K + kt + ((c ^ ((row >> 1) & 3)) * 8),
                  dst + (size_t)cb * 8);
    }
#pragma unroll
    for (int i = 0; i < 2; ++i) {
      const int cb = i * 512 + wid * 64;
      const int ch = cb + lane;
      const int row = ch >> 2, c = ch & 3;
      gload_lds16(gB + (size_t)row * K + kt + ((c ^ ((row >> 1) & 3)) * 8),
                  dst + 8192 + (size_t)cb * 8);
    }
  };

  f32x4 acc[8][4] = {};
  short8 aF[4], bF[4];

  const int nt = K >> 5;
  stage(smem, 0);
  stage(smem + 16384, 32);
  WAIT_VM4();
  BAR();

  int cs = 0;
  for (int t = 0; t < nt; ++t) {
    ushort* cA = smem + cs * 16384;
    ushort* cB = cA + 8192;
    int ss = cs + 2; if (ss >= 3) ss -= 3;
    const bool pf2 = (t + 2 < nt);
    if (pf2) stage(smem + ss * 16384, (t + 2) * 32);
#pragma unroll
    for (int mm = 0; mm < 4; ++mm) {
      const int row = wr * 128 + mm * 16 + llo;
      aF[mm] = *(const short8*)&cA[row * 32 + ((lhi ^ ((row >> 1) & 3)) * 8)];
    }
#pragma unroll
    for (int nn = 0; nn < 4; ++nn) {
      const int row = wc * 64 + nn * 16 + llo;
      bF[nn] = *(const short8*)&cB[row * 32 + ((lhi ^ ((row >> 1) & 3)) * 8)];
    }
    BAR(); WAIT_LGKM();
    __builtin_amdgcn_s_setprio(1);
#pragma unroll
    for (int mm = 0; mm < 4; ++mm)
#pragma unroll
      for (int nn = 0; nn < 4; ++nn)
        acc[mm][nn] = mfma16(aF[mm], bF[nn], acc[mm][nn]);
    __builtin_amdgcn_s_setprio(0);
    BAR();
#pragma unroll
    for (int mm = 0; mm < 4; ++mm) {
      const int row = wr * 128 + (mm + 4) * 16 + llo;
      aF[mm] = *(const short8*)&cA[row * 32 + ((lhi ^ ((row >> 1) & 3)) * 8)];
    }
    BAR(); WAIT_LGKM();
    __builtin_amdgcn_s_setprio(1);
#pragma unroll
    for (int mm = 0; mm < 4; ++mm)
#pragma unroll
      for (int nn = 0; nn < 4; ++nn)
        acc[mm + 4][nn] = mfma16(aF[mm], bF[nn], acc[mm + 4][nn]);
    __builtin_amdgcn_s_setprio(0);
    if (pf2) { WAIT_VM4(); } else { WAIT_VM0(); }
    BAR();
    ++cs; if (cs == 3) cs = 0;
  }

#pragma unroll
  for (int m = 0; m < 8; ++m) {
#pragma unroll
    for (int n = 0; n < 4; ++n) {
      const int col = bn0 + wc * 64 + n * 16 + llo;
#pragma unroll
      for (int r = 0; r < 4; ++r) {
        const int row = bm0 + wr * 128 + m * 16 + lhi * 4 + r;
        float v = acc[m][n][r];
        if constexpr (EPI == 3) {
          // interleaved upT rows: even col = gate_j, odd col = up_j, j = col>>1
          const float other = __shfl_xor(v, 1);
          if ((llo & 1) == 0) {
            const float gate = v, up = other;
            const float hh = up * gate / (1.f + expf(-gate));
            ((ushort*)Cout)[(size_t)row * (N >> 1) + (col >> 1)] = f2bf(hh);
          }
        } else {
          ((float*)Cout)[(size_t)row * N + col] = v;
        }
      }
    }
  }
}

// ---------- launch ----------
extern "C" void kernel_launch(void* const* d_in, const int* in_sizes, int n_in,
                              void* d_out, int out_size, void* d_ws, size_t ws_size,
                              hipStream_t stream) {
  const int* tokens    = (const int*)d_in[0];
  const float* table   = (const float*)d_in[1];
  const float* qkv_w   = (const float*)d_in[2];
  const float* out_w   = (const float*)d_in[3];
  const float* up_w    = (const float*)d_in[4];
  const float* down_w  = (const float*)d_in[5];
  const float* vocab_w = (const float*)d_in[6];
  float* logits = (float*)d_out;

  constexpr int G8P_LDS = 98304;
  hipFuncSetAttribute(reinterpret_cast<const void*>(&gemm8p_kernel<0>),
                      hipFuncAttributeMaxDynamicSharedMemorySize, G8P_LDS);
  hipFuncSetAttribute(reinterpret_cast<const void*>(&gemm8p_kernel<3>),
                      hipFuncAttributeMaxDynamicSharedMemorySize, G8P_LDS);

  char* p = (char*)d_ws;
  auto alloc = [&](size_t bytes) {
    char* r = p;
    p += (bytes + 255) & ~(size_t)255;
    return r;
  };
  float*  emb    = (float*)alloc(2048ull * 1024 * 4);
  ushort* normed = (ushort*)alloc(2048ull * 1024 * 2);
  float2* cstab  = (float2*)alloc(2048ull * 32 * 8);
  ushort* qhb    = (ushort*)alloc(16ull * 2048 * 64 * 2);
  ushort* khb    = (ushort*)alloc(16ull * 2048 * 64 * 2);
  ushort* vtb    = (ushort*)alloc(16ull * 64 * 2048 * 2);
  ushort* attno  = (ushort*)alloc(2048ull * 1024 * 2);
  float*  wso    = (float*)alloc(2ull * 16 * 2048 * 64 * 4);
  float*  wsml   = (float*)alloc(2ull * 16 * 2048 * 2 * 4);
  ushort* hbuf   = (ushort*)alloc(2048ull * 4096 * 2);
  ushort* qkvT   = (ushort*)alloc(4ull * 3072 * 1024 * 2);
  ushort* outT   = (ushort*)alloc(4ull * 1024 * 1024 * 2);
  ushort* upT    = (ushort*)alloc(4ull * 8192 * 1024 * 2);
  ushort* downT  = (ushort*)alloc(4ull * 1024 * 4096 * 2);
  ushort* vocabT = (ushort*)alloc(32000ull * 1024 * 2);

  // batched weight transposes (z = layer) + RoPE table
  transpose_conv_kernel<<<dim3(3072 / 64, 1024 / 64, 4), 256, 0, stream>>>(
      qkv_w, qkvT, 1024, 3072, 0);
  transpose_conv_kernel<<<dim3(1024 / 64, 1024 / 64, 4), 256, 0, stream>>>(
      out_w, outT, 1024, 1024, 0);
  transpose_conv_kernel<<<dim3(8192 / 64, 1024 / 64, 4), 256, 0, stream>>>(
      up_w, upT, 1024, 8192, 1);
  transpose_conv_kernel<<<dim3(1024 / 64, 4096 / 64, 4), 256, 0, stream>>>(
      down_w, downT, 4096, 1024, 0);
  transpose_conv_kernel<<<dim3(32000 / 64, 1024 / 64, 1), 256, 0, stream>>>(
      vocab_w, vocabT, 1024, 32000, 0);
  sincos_kernel<<<256, 256, 0, stream>>>(cstab);

  embed_norm_kernel<<<2048, 256, 0, stream>>>(tokens, table, emb, normed);

  for (int l = 0; l < 4; ++l) {
    if (l > 0) rmsnorm_kernel<<<2048, 256, 0, stream>>>(emb, normed);
    gemm_qkv_kernel<<<dim3(3072 / 128, 2048 / 128), 256, 0, stream>>>(
        normed, qkvT + (size_t)l * 3072 * 1024, cstab, qhb, khb, vtb, 1024);
    attn_mfma_kernel<<<dim3(32, 16), 512, 0, stream>>>(qhb, khb, vtb, wso, wsml);
    attn_merge_kernel<<<2048, 256, 0, stream>>>(wso, wsml, attno);
    gemm_bt64_kernel<64, 128, 1><<<dim3(1024 / 128, 2048 / 64), 256, 0, stream>>>(
        attno, outT + (size_t)l * 1024 * 1024, emb, emb, 2048, 1024, 1024);
    rmsnorm_kernel<<<2048, 256, 0, stream>>>(emb, normed);
    gemm8p_kernel<3><<<(8192 / 256) * (2048 / 256), 512, G8P_LDS, stream>>>(
        normed, upT + (size_t)l * 8192 * 1024, hbuf, 2048, 8192, 1024, 2048 / 256);
    gemm_bt64_kernel<64, 128, 1><<<dim3(1024 / 128, 2048 / 64), 256, 0, stream>>>(
        hbuf, downT + (size_t)l * 1024 * 4096, emb, emb, 2048, 1024, 4096);
  }
  rmsnorm_kernel<<<2048, 256, 0, stream>>>(emb, normed);
  gemm8p_kernel<0><<<(32000 / 256) * (2048 / 256), 512, G8P_LDS, stream>>>(
      normed, vocabT, logits, 2048, 32000, 1024, 2048 / 256);
}

// Round 18
// 1160.892 us; speedup vs baseline: 1.1085x; 1.0262x over previous
//
#include <hip/hip_runtime.h>
#include <hip/hip_bf16.h>

// ---------- types ----------
typedef __attribute__((ext_vector_type(8))) short short8;   // 8 x bf16 bits
typedef __attribute__((ext_vector_type(4))) float f32x4;

__device__ __forceinline__ ushort f2bf(float f) {
  uint32_t u = __float_as_uint(f);
  uint32_t r = (u + 0x7FFFu + ((u >> 16) & 1u)) >> 16;
  return (ushort)r;
}
__device__ __forceinline__ float bf2f(ushort u) {
  return __uint_as_float(((uint32_t)u) << 16);
}

__device__ __forceinline__ void gload_lds16(const ushort* g, ushort* l) {
  __builtin_amdgcn_global_load_lds(
      (const __attribute__((address_space(1))) void*)g,
      (__attribute__((address_space(3))) void*)l, 16, 0, 0);
}

__device__ __forceinline__ f32x4 mfma16(short8 a, short8 b, f32x4 c) {
  return __builtin_amdgcn_mfma_f32_16x16x32_bf16(a, b, c, 0, 0, 0);
}

#define BAR() __builtin_amdgcn_s_barrier()
#define WAIT_LGKM()                                        \
  do {                                                     \
    asm volatile("s_waitcnt lgkmcnt(0)" ::: "memory");     \
    __builtin_amdgcn_sched_barrier(0);                     \
  } while (0)
#define WAIT_VM0()                                         \
  do {                                                     \
    asm volatile("s_waitcnt vmcnt(0)" ::: "memory");       \
    __builtin_amdgcn_sched_barrier(0);                     \
  } while (0)
#define WAIT_VM4()                                         \
  do {                                                     \
    asm volatile("s_waitcnt vmcnt(4)" ::: "memory");       \
    __builtin_amdgcn_sched_barrier(0);                     \
  } while (0)

// ---------- transpose + fp32->bf16 convert: W[K][N] -> WT[p(N)][K] ----------
// 64x64 tiles, float4 loads / ushort4 stores. blockIdx.z = layer.
// mode 0: p(n)=n.  mode 1 (gate/up interleave): p(n)= n<4096 ? 2n : 2(n-4096)+1
__global__ __launch_bounds__(256)
void transpose_conv_kernel(const float* __restrict__ W, ushort* __restrict__ WT,
                           const int K, const int N, const int mode) {
  const size_t lofs = (size_t)blockIdx.z * K * N;
  W += lofs;
  WT += lofs;
  __shared__ float tile[64][65];
  const int n0 = blockIdx.x * 64;
  const int k0 = blockIdx.y * 64;
  const int t = threadIdx.x;
#pragma unroll
  for (int j = 0; j < 4; ++j) {
    const int idx = j * 1024 + t * 4;
    const int kk = idx >> 6, nn = idx & 63;
    *(float4*)&tile[kk][nn] = *(const float4*)&W[(size_t)(k0 + kk) * N + n0 + nn];
  }
  __syncthreads();
#pragma unroll
  for (int j = 0; j < 4; ++j) {
    const int idx = j * 1024 + t * 4;
    const int nn = idx >> 6, kk = idx & 63;
    int rr = n0 + nn;
    if (mode == 1) rr = (rr < 4096) ? (2 * rr) : (2 * (rr - 4096) + 1);
    ushort4 o;
    o.x = f2bf(tile[kk + 0][nn]);
    o.y = f2bf(tile[kk + 1][nn]);
    o.z = f2bf(tile[kk + 2][nn]);
    o.w = f2bf(tile[kk + 3][nn]);
    *(ushort4*)&WT[(size_t)rr * K + k0 + kk] = o;
  }
}

// ---------- RoPE cos/sin table ----------
__global__ __launch_bounds__(256)
void sincos_kernel(float2* __restrict__ cstab) {
  const int idx = blockIdx.x * 256 + threadIdx.x;   // 65536 total
  const int s = idx >> 5, o = idx & 31;
  const float freq = exp2f(-0.41524101186092029f * (float)o);  // 10000^(-o/32)
  const float a = (float)s * freq;
  cstab[idx] = make_float2(cosf(a), sinf(a));
}

// ---------- fused embedding gather + rmsnorm (table row 0 forced to zero) ----------
__global__ __launch_bounds__(256)
void embed_norm_kernel(const int* __restrict__ tokens, const float* __restrict__ table,
                       float* __restrict__ emb, ushort* __restrict__ normed) {
  const int s = blockIdx.x, t = threadIdx.x;
  const int tok = tokens[s];
  float4 v = make_float4(0.f, 0.f, 0.f, 0.f);
  if (tok != 0) v = *(const float4*)&table[(size_t)tok * 1024 + t * 4];
  *(float4*)&emb[(size_t)s * 1024 + t * 4] = v;
  float ss = v.x * v.x + v.y * v.y + v.z * v.z + v.w * v.w;
#pragma unroll
  for (int off = 32; off; off >>= 1) ss += __shfl_xor(ss, off);
  __shared__ float red[4];
  if ((t & 63) == 0) red[t >> 6] = ss;
  __syncthreads();
  const float total = red[0] + red[1] + red[2] + red[3];
  const float sc = rsqrtf(total * (1.f / 1024.f) + 1e-5f);
  ushort4 o;
  o.x = f2bf(v.x * sc); o.y = f2bf(v.y * sc);
  o.z = f2bf(v.z * sc); o.w = f2bf(v.w * sc);
  *(ushort4*)&normed[(size_t)s * 1024 + t * 4] = o;
}

// ---------- rmsnorm over 1024 cols: f32 in -> bf16 out ----------
__global__ __launch_bounds__(256)
void rmsnorm_kernel(const float* __restrict__ x, ushort* __restrict__ out) {
  const int row = blockIdx.x, t = threadIdx.x;
  const float4 v = *(const float4*)&x[(size_t)row * 1024 + t * 4];
  float ss = v.x * v.x + v.y * v.y + v.z * v.z + v.w * v.w;
#pragma unroll
  for (int off = 32; off; off >>= 1) ss += __shfl_xor(ss, off);
  __shared__ float red[4];
  if ((t & 63) == 0) red[t >> 6] = ss;
  __syncthreads();
  const float total = red[0] + red[1] + red[2] + red[3];
  const float sc = rsqrtf(total * (1.f / 1024.f) + 1e-5f);
  ushort4 o;
  o.x = f2bf(v.x * sc); o.y = f2bf(v.y * sc);
  o.z = f2bf(v.z * sc); o.w = f2bf(v.w * sc);
  *(ushort4*)&out[(size_t)row * 1024 + t * 4] = o;
}

// ---------- MFMA flash attention, causal, SPLIT-K, double-buffered K/V ----------
// block = (128-row Q-tile, key-half, head); 512 threads = 8 waves, each wave
// 16 q-rows. half 0: chunks [0, qt+1); half 1: chunks [qt+1, 2qt+2) -> equal
// work per half. Pairing qt=(h<8)?u:15-u makes co-resident pair work constant.
// K/V double-buffered: chunk t+1's global_load_lds issued BEFORE chunk t's
// compute; the single __syncthreads() per chunk (implicit vmcnt drain) both
// lands buf^1 and fences reads of buf before the next iteration overwrites it.
// Partial (o,m,l) unnormalized to workspace; attn_merge combines halves.
__global__ __launch_bounds__(512)
void attn_mfma_kernel(const ushort* __restrict__ qh, const ushort* __restrict__ kh,
                      const ushort* __restrict__ vt, float* __restrict__ wso,
                      float* __restrict__ wsml) {
  __shared__ ushort sQ[128 * 64];
  __shared__ ushort sK[2][64 * 64];
  __shared__ ushort sV[2][64 * 64];  // V^T: rows = d, cols = key
  __shared__ ushort sP[8][1024];     // per-wave P [16 qrow][64 key]
  const int h = blockIdx.y;
  const int u = blockIdx.x;          // 0..31 = (qt_raw, half)
  const int qt_raw = u >> 1, half = u & 1;
  const int qt = (h < 8) ? qt_raw : 15 - qt_raw;   // causal load-balance pairing
  const int i0 = qt * 128;
  const int tid = threadIdx.x;
  const int w = tid >> 6, lane = tid & 63;
  const int llo = lane & 15, lhi = lane >> 4;
  const ushort* qg = qh + ((size_t)h * 2048 + i0) * 64;
  const ushort* kg = kh + (size_t)h * 2048 * 64;
  const ushort* vg = vt + (size_t)h * 64 * 2048;

  // per-wave 16B-chunk coords for K/V staging (one 64-chunk region per wave)
  const int scb = w * 64;
  const int sch = scb + lane;
  const int srow = sch >> 3, sc = sch & 7;
  auto stage_kv = [&](int kb, int b) {
    gload_lds16(kg + (size_t)(kb + srow) * 64 + ((sc ^ (srow & 7)) * 8),
                &sK[b][scb * 8]);
    gload_lds16(vg + (size_t)srow * 2048 + kb + ((sc ^ (srow & 7)) * 8),
                &sV[b][scb * 8]);
  };

  const int c0 = half ? (qt + 1) : 0;
  const int c1 = half ? (2 * qt + 2) : (qt + 1);

  // prologue: stage Q tile + first K/V chunk; one barrier drains both
#pragma unroll
  for (int j = 0; j < 2; ++j) {
    const int cb = j * 512 + w * 64;
    const int ch = cb + lane;
    const int row = ch >> 3, c = ch & 7;
    gload_lds16(qg + (size_t)row * 64 + ((c ^ (row & 7)) * 8), &sQ[cb * 8]);
  }
  stage_kv(c0 * 64, 0);
  __syncthreads();
  const int qrow = w * 16 + llo;     // tile-local q row this lane owns (as N col)
  const short8 qf0 = *(const short8*)&sQ[qrow * 64 + ((lhi ^ (qrow & 7)) * 8)];
  const short8 qf1 = *(const short8*)&sQ[qrow * 64 + (((4 + lhi) ^ (qrow & 7)) * 8)];
  const int wmax = i0 + w * 16 + 15; // wave's last (largest) q row

  float m = -1e30f, lsum = 0.f;
  f32x4 o[4] = {};                   // out frags: col=d=nn*16+llo, row=qrow=lhi*4+r
  int bufc = 0;
  for (int cb2 = c0; cb2 < c1; ++cb2) {
    const int kb = cb2 * 64;
    if (cb2 + 1 < c1) stage_kv((cb2 + 1) * 64, bufc ^ 1);   // issue next early

    if (kb <= wmax) {                // wave-uniform causal skip
      f32x4 st[4] = {};
#pragma unroll
      for (int ck = 0; ck < 2; ++ck) {
        const short8 qf = ck ? qf1 : qf0;
#pragma unroll
        for (int f = 0; f < 4; ++f) {
          const int key = f * 16 + llo;
          const short8 kf = *(const short8*)&sK[bufc][key * 64 + (((ck * 4 + lhi) ^ (key & 7)) * 8)];
          st[f] = mfma16(kf, qf, st[f]);
        }
      }

      float pv[4][4];
      const bool edge = (kb + 63 > i0 + w * 16);   // boundary chunk needs masking
#pragma unroll
      for (int f = 0; f < 4; ++f)
#pragma unroll
        for (int r = 0; r < 4; ++r) {
          float x = st[f][r] * 0.125f;
          if (edge && (kb - i0 + f * 16 + lhi * 4 + r) > qrow) x = -1e30f;
          pv[f][r] = x;
        }
      float mr = pv[0][0];
#pragma unroll
      for (int f = 0; f < 4; ++f)
#pragma unroll
        for (int r = 0; r < 4; ++r) mr = fmaxf(mr, pv[f][r]);
      mr = fmaxf(mr, __shfl_xor(mr, 16));
      mr = fmaxf(mr, __shfl_xor(mr, 32));
      const float mnew = fmaxf(m, mr);
      const float scale = __expf(m - mnew);
      m = mnew;
      float rs = 0.f;
#pragma unroll
      for (int f = 0; f < 4; ++f)
#pragma unroll
        for (int r = 0; r < 4; ++r) {
          const float p = __expf(pv[f][r] - mnew);
          pv[f][r] = p;
          rs += p;
        }
      rs += __shfl_xor(rs, 16);
      rs += __shfl_xor(rs, 32);
      lsum = lsum * scale + rs;
      float scr[4];
#pragma unroll
      for (int r = 0; r < 4; ++r) scr[r] = __shfl(scale, lhi * 4 + r);
#pragma unroll
      for (int nn = 0; nn < 4; ++nn)
#pragma unroll
        for (int r = 0; r < 4; ++r) o[nn][r] *= scr[r];

      ushort* pw = sP[w];
#pragma unroll
      for (int f = 0; f < 4; ++f) {
        uint2 pk;
        pk.x = (uint)f2bf(pv[f][0]) | ((uint)f2bf(pv[f][1]) << 16);
        pk.y = (uint)f2bf(pv[f][2]) | ((uint)f2bf(pv[f][3]) << 16);
        *(uint2*)&pw[llo * 64 + ((f * 16 + lhi * 4) ^ ((llo & 7) << 3))] = pk;
      }
      const short8 pf0 = *(const short8*)&pw[llo * 64 + ((lhi ^ (llo & 7)) * 8)];
      const short8 pf1 = *(const short8*)&pw[llo * 64 + (((4 + lhi) ^ (llo & 7)) * 8)];

#pragma unroll
      for (int ck = 0; ck < 2; ++ck) {
        const short8 pf = ck ? pf1 : pf0;
#pragma unroll
        for (int nn = 0; nn < 4; ++nn) {
          const int drow = nn * 16 + llo;
          const short8 vf = *(const short8*)&sV[bufc][drow * 64 + (((ck * 4 + lhi) ^ (drow & 7)) * 8)];
          o[nn] = mfma16(pf, vf, o[nn]);
        }
      }
    }

    __syncthreads();   // drains vmcnt (buf^1 landed) + fences reads of bufc
    bufc ^= 1;
  }

  // partial store (unnormalized): o -> wso[half][h][row][d], (m,l) -> wsml
#pragma unroll
  for (int nn = 0; nn < 4; ++nn)
#pragma unroll
    for (int r = 0; r < 4; ++r) {
      const int row = i0 + w * 16 + lhi * 4 + r;
      wso[((size_t)(half * 16 + h) * 2048 + row) * 64 + nn * 16 + llo] = o[nn][r];
    }
  if (lhi == 0) {
    const int row = i0 + w * 16 + llo;
    *(float2*)&wsml[((size_t)(half * 16 + h) * 2048 + row) * 2] = make_float2(m, lsum);
  }
}

// ---------- merge the two key-half partials -> bf16 attn_out ----------
__global__ __launch_bounds__(256)
void attn_merge_kernel(const float* __restrict__ wso, const float* __restrict__ wsml,
                       ushort* __restrict__ attn_out) {
  const int row = blockIdx.x;
  const int t = threadIdx.x;
  const int h = t >> 4, dg = t & 15;
  const float2 ml1 = *(const float2*)&wsml[((size_t)h * 2048 + row) * 2];
  const float2 ml2 = *(const float2*)&wsml[((size_t)(16 + h) * 2048 + row) * 2];
  const float m = fmaxf(ml1.x, ml2.x);
  const float w1 = __expf(ml1.x - m), w2 = __expf(ml2.x - m);
  const float inv = 1.f / (ml1.y * w1 + ml2.y * w2);
  const float4 o1 = *(const float4*)&wso[((size_t)h * 2048 + row) * 64 + dg * 4];
  const float4 o2 = *(const float4*)&wso[((size_t)(16 + h) * 2048 + row) * 64 + dg * 4];
  ushort4 o;
  o.x = f2bf((o1.x * w1 + o2.x * w2) * inv);
  o.y = f2bf((o1.y * w1 + o2.y * w2) * inv);
  o.z = f2bf((o1.z * w1 + o2.z * w2) * inv);
  o.w = f2bf((o1.w * w1 + o2.w * w2) * inv);
  *(ushort4*)&attn_out[(size_t)row * 1024 + h * 64 + dg * 4] = o;
}

// ---------- 2-phase bf16 MFMA GEMM, BK=64, XOR-swizzled, double-buffered ----------
// C[M][N] = A[M][K] * BT[N][K]^T (+addend). 256 threads = 4 waves (2M x 2N).
// LDS double-buffered: stage(t+1) issued before compute(t); single
// __syncthreads() per K-tile (implicit vmcnt drain lands buf^1 + fences buf).
// EPI: 0 = f32 store, 1 = f32 addend + store
template <int BM, int BN, int EPI>
__global__ __launch_bounds__(256)
void gemm_bt64_kernel(const ushort* __restrict__ A, const ushort* __restrict__ BT,
                      const float* __restrict__ addend, void* __restrict__ Cout,
                      const int M, const int N, const int K) {
  constexpr int WM = BM / 2, WN = BN / 2;
  constexpr int FM = WM / 16, FN = WN / 16;
  __shared__ ushort sA[2][BM * 64];
  __shared__ ushort sB[2][BN * 64];
  const int bm0 = blockIdx.y * BM;
  const int bn0 = blockIdx.x * BN;
  const int tid = threadIdx.x;
  const int wid = tid >> 6, lane = tid & 63;
  const int wr = wid >> 1, wc = wid & 1;
  const int lhi = lane >> 4, llo = lane & 15;

  auto stage = [&](int kt, int b) {
#pragma unroll
    for (int i = 0; i < BM * 8 / 256; ++i) {
      const int cb = i * 256 + wid * 64;        // wave-uniform base chunk
      const int ch = cb + lane;
      const int row = ch >> 3, c = ch & 7;
      gload_lds16(A + (size_t)(bm0 + row) * K + kt + ((c ^ (row & 7)) * 8),
                  &sA[b][(size_t)cb * 8]);
    }
#pragma unroll
    for (int i = 0; i < BN * 8 / 256; ++i) {
      const int cb = i * 256 + wid * 64;
      const int ch = cb + lane;
      const int row = ch >> 3, c = ch & 7;
      gload_lds16(BT + (size_t)(bn0 + row) * K + kt + ((c ^ (row & 7)) * 8),
                  &sB[b][(size_t)cb * 8]);
    }
  };

  f32x4 acc[FM][FN] = {};
  const int nt = K >> 6;
  stage(0, 0);
  __syncthreads();
  int buf = 0;
  for (int t = 0; t < nt; ++t) {
    if (t + 1 < nt) stage((t + 1) * 64, buf ^ 1);   // issue next early
    short8 aF[FM][2], bF[FN][2];
#pragma unroll
    for (int mm = 0; mm < FM; ++mm) {
      const int row = wr * WM + mm * 16 + llo;
#pragma unroll
      for (int ks = 0; ks < 2; ++ks)
        aF[mm][ks] = *(const short8*)&sA[buf][row * 64 + (((ks * 4 + lhi) ^ (row & 7)) * 8)];
    }
#pragma unroll
    for (int nn = 0; nn < FN; ++nn) {
      const int row = wc * WN + nn * 16 + llo;
#pragma unroll
      for (int ks = 0; ks < 2; ++ks)
        bF[nn][ks] = *(const short8*)&sB[buf][row * 64 + (((ks * 4 + lhi) ^ (row & 7)) * 8)];
    }
#pragma unroll
    for (int mm = 0; mm < FM; ++mm)
#pragma unroll
      for (int nn = 0; nn < FN; ++nn)
#pragma unroll
        for (int ks = 0; ks < 2; ++ks)
          acc[mm][nn] = mfma16(aF[mm][ks], bF[nn][ks], acc[mm][nn]);
    __syncthreads();   // drains vmcnt (buf^1 landed) + fences reads of buf
    buf ^= 1;
  }
#pragma unroll
  for (int mm = 0; mm < FM; ++mm) {
#pragma unroll
    for (int nn = 0; nn < FN; ++nn) {
      const int col = bn0 + wc * WN + nn * 16 + llo;
#pragma unroll
      for (int r = 0; r < 4; ++r) {
        const int row = bm0 + wr * WM + mm * 16 + lhi * 4 + r;
        float v = acc[mm][nn][r];
        if constexpr (EPI == 1) v += addend[(size_t)row * N + col];
        ((float*)Cout)[(size_t)row * N + col] = v;
      }
    }
  }
}

// ---------- qkv GEMM 128x128 BK=64, double-buffered, fused RoPE + V^T ----------
__global__ __launch_bounds__(256)
void gemm_qkv_kernel(const ushort* __restrict__ A, const ushort* __restrict__ BT,
                     const float2* __restrict__ cstab, ushort* __restrict__ qh,
                     ushort* __restrict__ kh, ushort* __restrict__ vt, const int K) {
  constexpr int BM = 128, BN = 128, WM = 64, WN = 64, FM = 4, FN = 4;
  __shared__ ushort sA[2][BM * 64];
  __shared__ ushort sB[2][BN * 64];
  const int bm0 = blockIdx.y * BM;
  const int bn0 = blockIdx.x * BN;
  const int tid = threadIdx.x;
  const int wid = tid >> 6, lane = tid & 63;
  const int wr = wid >> 1, wc = wid & 1;
  const int lhi = lane >> 4, llo = lane & 15;

  auto stage = [&](int kt, int b) {
#pragma unroll
    for (int i = 0; i < 4; ++i) {
      const int cb = i * 256 + wid * 64;
      const int ch = cb + lane;
      const int row = ch >> 3, c = ch & 7;
      gload_lds16(A + (size_t)(bm0 + row) * K + kt + ((c ^ (row & 7)) * 8),
                  &sA[b][(size_t)cb * 8]);
    }
#pragma unroll
    for (int i = 0; i < 4; ++i) {
      const int cb = i * 256 + wid * 64;
      const int ch = cb + lane;
      const int row = ch >> 3, c = ch & 7;
      gload_lds16(BT + (size_t)(bn0 + row) * K + kt + ((c ^ (row & 7)) * 8),
                  &sB[b][(size_t)cb * 8]);
    }
  };

  f32x4 acc[FM][FN] = {};
  const int nt = K >> 6;
  stage(0, 0);
  __syncthreads();
  int buf = 0;
  for (int t = 0; t < nt; ++t) {
    if (t + 1 < nt) stage((t + 1) * 64, buf ^ 1);   // issue next early
    short8 aF[FM][2], bF[FN][2];
#pragma unroll
    for (int mm = 0; mm < FM; ++mm) {
      const int row = wr * WM + mm * 16 + llo;
#pragma unroll
      for (int ks = 0; ks < 2; ++ks)
        aF[mm][ks] = *(const short8*)&sA[buf][row * 64 + (((ks * 4 + lhi) ^ (row & 7)) * 8)];
    }
#pragma unroll
    for (int nn = 0; nn < FN; ++nn) {
      const int row = wc * WN + nn * 16 + llo;
#pragma unroll
      for (int ks = 0; ks < 2; ++ks)
        bF[nn][ks] = *(const short8*)&sB[buf][row * 64 + (((ks * 4 + lhi) ^ (row & 7)) * 8)];
    }
#pragma unroll
    for (int mm = 0; mm < FM; ++mm)
#pragma unroll
      for (int nn = 0; nn < FN; ++nn)
#pragma unroll
        for (int ks = 0; ks < 2; ++ks)
          acc[mm][nn] = mfma16(aF[mm][ks], bF[nn][ks], acc[mm][nn]);
    __syncthreads();   // drains vmcnt (buf^1 landed) + fences reads of buf
    buf ^= 1;
  }
  // epilogue
#pragma unroll
  for (int mm = 0; mm < FM; ++mm) {
    const int row_base = bm0 + wr * WM + mm * 16 + lhi * 4;
#pragma unroll
    for (int nn = 0; nn < FN; ++nn) {
      const int col = bn0 + wc * WN + nn * 16 + llo;
      const int part = col >> 10;
      const int hcol = col & 1023;
      const int h = hcol >> 6;
      const int d = hcol & 63;
      const int off = d & 31;
      if (part == 2) {
        ushort4 o;
        o.x = f2bf(acc[mm][nn][0]);
        o.y = f2bf(acc[mm][nn][1]);
        o.z = f2bf(acc[mm][nn][2]);
        o.w = f2bf(acc[mm][nn][3]);
        *(ushort4*)&vt[((size_t)h * 64 + d) * 2048 + row_base] = o;
      } else {
#pragma unroll
        for (int r = 0; r < 4; ++r) {
          const int row = row_base + r;
          const float v = acc[mm][nn][r];
          const float pt = acc[mm][nn ^ 2][r];
          const float2 cn = cstab[row * 32 + off];
          const float si = (d < 32) ? -cn.y : cn.y;
          const ushort o = f2bf(cn.x * v + si * pt);
          const size_t ho = ((size_t)h * 2048 + row) * 64 + d;
          if (part == 0) qh[ho] = o; else kh[ho] = o;
        }
      }
    }
  }
}

// ---------- gemm8p: 256x256 BK=32, 3-stage LDS, depth-2 counted-vmcnt ----------
// EPI: 0 = f32 store (vocab), 3 = fused SiLU on interleaved gate/up -> bf16 (up)
template <int EPI>
__global__ __launch_bounds__(512, 2)
void gemm8p_kernel(const ushort* __restrict__ A, const ushort* __restrict__ BT,
                   void* __restrict__ Cout,
                   const int M, const int N, const int K, const int nby) {
  extern __shared__ ushort smem[];   // 3 x 16384 elements
  const int nwg = gridDim.x;
  const int cpx = nwg >> 3;
  int id = blockIdx.x;
  id = (id & 7) * cpx + (id >> 3);   // bijective XCD swizzle (nwg%8==0)
  const int by = id % nby, bx = id / nby;   // by-major: intra-XCD B-panel reuse
  const int bm0 = by * 256, bn0 = bx * 256;
  const int tid = threadIdx.x;
  const int wid = tid >> 6, lane = tid & 63;
  const int wr = wid >> 2, wc = wid & 3;
  const int llo = lane & 15, lhi = lane >> 4;
  const ushort* gA = A + (size_t)bm0 * K;
  const ushort* gB = BT + (size_t)bn0 * K;

  auto stage = [&](ushort* dst, int kt) {
#pragma unroll
    for (int i = 0; i < 2; ++i) {
      const int cb = i * 512 + wid * 64;       // wave-uniform base chunk
      const int ch = cb + lane;
      const int row = ch >> 2, c = ch & 3;
      gload_lds16(gA + (size_t)row * K + kt + ((c ^ ((row >> 1) & 3)) * 8),
                  dst + (size_t)cb * 8);
    }
#pragma unroll
    for (int i = 0; i < 2; ++i) {
      const int cb = i * 512 + wid * 64;
      const int ch = cb + lane;
      const int row = ch >> 2, c = ch & 3;
      gload_lds16(gB + (size_t)row * K + kt + ((c ^ ((row >> 1) & 3)) * 8),
                  dst + 8192 + (size_t)cb * 8);
    }
  };

  f32x4 acc[8][4] = {};
  short8 aF[4], bF[4];

  const int nt = K >> 5;
  stage(smem, 0);
  stage(smem + 16384, 32);
  WAIT_VM4();
  BAR();

  int cs = 0;
  for (int t = 0; t < nt; ++t) {
    ushort* cA = smem + cs * 16384;
    ushort* cB = cA + 8192;
    int ss = cs + 2; if (ss >= 3) ss -= 3;
    const bool pf2 = (t + 2 < nt);
    if (pf2) stage(smem + ss * 16384, (t + 2) * 32);
#pragma unroll
    for (int mm = 0; mm < 4; ++mm) {
      const int row = wr * 128 + mm * 16 + llo;
      aF[mm] = *(const short8*)&cA[row * 32 + ((lhi ^ ((row >> 1) & 3)) * 8)];
    }
#pragma unroll
    for (int nn = 0; nn < 4; ++nn) {
      const int row = wc * 64 + nn * 16 + llo;
      bF[nn] = *(const short8*)&cB[row * 32 + ((lhi ^ ((row >> 1) & 3)) * 8)];
    }
    BAR(); WAIT_LGKM();
    __builtin_amdgcn_s_setprio(1);
#pragma unroll
    for (int mm = 0; mm < 4; ++mm)
#pragma unroll
      for (int nn = 0; nn < 4; ++nn)
        acc[mm][nn] = mfma16(aF[mm], bF[nn], acc[mm][nn]);
    __builtin_amdgcn_s_setprio(0);
    BAR();
#pragma unroll
    for (int mm = 0; mm < 4; ++mm) {
      const int row = wr * 128 + (mm + 4) * 16 + llo;
      aF[mm] = *(const short8*)&cA[row * 32 + ((lhi ^ ((row >> 1) & 3)) * 8)];
    }
    BAR(); WAIT_LGKM();
    __builtin_amdgcn_s_setprio(1);
#pragma unroll
    for (int mm = 0; mm < 4; ++mm)
#pragma unroll
      for (int nn = 0; nn < 4; ++nn)
        acc[mm + 4][nn] = mfma16(aF[mm], bF[nn], acc[mm + 4][nn]);
    __builtin_amdgcn_s_setprio(0);
    if (pf2) { WAIT_VM4(); } else { WAIT_VM0(); }
    BAR();
    ++cs; if (cs == 3) cs = 0;
  }

#pragma unroll
  for (int m = 0; m < 8; ++m) {
#pragma unroll
    for (int n = 0; n < 4; ++n) {
      const int col = bn0 + wc * 64 + n * 16 + llo;
#pragma unroll
      for (int r = 0; r < 4; ++r) {
        const int row = bm0 + wr * 128 + m * 16 + lhi * 4 + r;
        float v = acc[m][n][r];
        if constexpr (EPI == 3) {
          // interleaved upT rows: even col = gate_j, odd col = up_j, j = col>>1
          const float other = __shfl_xor(v, 1);
          if ((llo & 1) == 0) {
            const float gate = v, up = other;
            const float hh = up * gate / (1.f + expf(-gate));
            ((ushort*)Cout)[(size_t)row * (N >> 1) + (col >> 1)] = f2bf(hh);
          }
        } else {
          ((float*)Cout)[(size_t)row * N + col] = v;
        }
      }
    }
  }
}

// ---------- launch ----------
extern "C" void kernel_launch(void* const* d_in, const int* in_sizes, int n_in,
                              void* d_out, int out_size, void* d_ws, size_t ws_size,
                              hipStream_t stream) {
  const int* tokens    = (const int*)d_in[0];
  const float* table   = (const float*)d_in[1];
  const float* qkv_w   = (const float*)d_in[2];
  const float* out_w   = (const float*)d_in[3];
  const float* up_w    = (const float*)d_in[4];
  const float* down_w  = (const float*)d_in[5];
  const float* vocab_w = (const float*)d_in[6];
  float* logits = (float*)d_out;

  constexpr int G8P_LDS = 98304;
  hipFuncSetAttribute(reinterpret_cast<const void*>(&gemm8p_kernel<0>),
                      hipFuncAttributeMaxDynamicSharedMemorySize, G8P_LDS);
  hipFuncSetAttribute(reinterpret_cast<const void*>(&gemm8p_kernel<3>),
                      hipFuncAttributeMaxDynamicSharedMemorySize, G8P_LDS);

  char* p = (char*)d_ws;
  auto alloc = [&](size_t bytes) {
    char* r = p;
    p += (bytes + 255) & ~(size_t)255;
    return r;
  };
  float*  emb    = (float*)alloc(2048ull * 1024 * 4);
  ushort* normed = (ushort*)alloc(2048ull * 1024 * 2);
  float2* cstab  = (float2*)alloc(2048ull * 32 * 8);
  ushort* qhb    = (ushort*)alloc(16ull * 2048 * 64 * 2);
  ushort* khb    = (ushort*)alloc(16ull * 2048 * 64 * 2);
  ushort* vtb    = (ushort*)alloc(16ull * 64 * 2048 * 2);
  ushort* attno  = (ushort*)alloc(2048ull * 1024 * 2);
  float*  wso    = (float*)alloc(2ull * 16 * 2048 * 64 * 4);
  float*  wsml   = (float*)alloc(2ull * 16 * 2048 * 2 * 4);
  ushort* hbuf   = (ushort*)alloc(2048ull * 4096 * 2);
  ushort* qkvT   = (ushort*)alloc(4ull * 3072 * 1024 * 2);
  ushort* outT   = (ushort*)alloc(4ull * 1024 * 1024 * 2);
  ushort* upT    = (ushort*)alloc(4ull * 8192 * 1024 * 2);
  ushort* downT  = (ushort*)alloc(4ull * 1024 * 4096 * 2);
  ushort* vocabT = (ushort*)alloc(32000ull * 1024 * 2);

  // batched weight transposes (z = layer) + RoPE table
  transpose_conv_kernel<<<dim3(3072 / 64, 1024 / 64, 4), 256, 0, stream>>>(
      qkv_w, qkvT, 1024, 3072, 0);
  transpose_conv_kernel<<<dim3(1024 / 64, 1024 / 64, 4), 256, 0, stream>>>(
      out_w, outT, 1024, 1024, 0);
  transpose_conv_kernel<<<dim3(8192 / 64, 1024 / 64, 4), 256, 0, stream>>>(
      up_w, upT, 1024, 8192, 1);
  transpose_conv_kernel<<<dim3(1024 / 64, 4096 / 64, 4), 256, 0, stream>>>(
      down_w, downT, 4096, 1024, 0);
  transpose_conv_kernel<<<dim3(32000 / 64, 1024 / 64, 1), 256, 0, stream>>>(
      vocab_w, vocabT, 1024, 32000, 0);
  sincos_kernel<<<256, 256, 0, stream>>>(cstab);

  embed_norm_kernel<<<2048, 256, 0, stream>>>(tokens, table, emb, normed);

  for (int l = 0; l < 4; ++l) {
    if (l > 0) rmsnorm_kernel<<<2048, 256, 0, stream>>>(emb, normed);
    gemm_qkv_kernel<<<dim3(3072 / 128, 2048 / 128), 256, 0, stream>>>(
        normed, qkvT + (size_t)l * 3072 * 1024, cstab, qhb, khb, vtb, 1024);
    attn_mfma_kernel<<<dim3(32, 16), 512, 0, stream>>>(qhb, khb, vtb, wso, wsml);
    attn_merge_kernel<<<2048, 256, 0, stream>>>(wso, wsml, attno);
    gemm_bt64_kernel<64, 128, 1><<<dim3(1024 / 128, 2048 / 64), 256, 0, stream>>>(
        attno, outT + (size_t)l * 1024 * 1024, emb, emb, 2048, 1024, 1024);
    rmsnorm_kernel<<<2048, 256, 0, stream>>>(emb, normed);
    gemm8p_kernel<3><<<(8192 / 256) * (2048 / 256), 512, G8P_LDS, stream>>>(
        normed, upT + (size_t)l * 8192 * 1024, hbuf, 2048, 8192, 1024, 2048 / 256);
    gemm_bt64_kernel<64, 128, 1><<<dim3(1024 / 128, 2048 / 64), 256, 0, stream>>>(
        hbuf, downT + (size_t)l * 1024 * 4096, emb, emb, 2048, 1024, 4096);
  }
  rmsnorm_kernel<<<2048, 256, 0, stream>>>(emb, normed);
  gemm8p_kernel<0><<<(32000 / 256) * (2048 / 256), 512, G8P_LDS, stream>>>(
      normed, vocabT, logits, 2048, 32000, 1024, 2048 / 256);
}